// Round 1
// baseline (835.843 us; speedup 1.0000x reference)
//
#include <hip/hip_runtime.h>
#include <math.h>

#define NROW 65536
#define NCOL 300
#define MDIM 9
#define DHALF 20
#define NTAPS (2*DHALF+1)   // 41
#define NITER 5
#define BLOCK 256
#define WPB 4               // waves per block
#define RPW 8               // rows per wave
#define NBLOCKS (NROW / (WPB * RPW))   // 2048

// ws float layout: [0,2700) = G (9x300); [2700,5400) = H = Sinv*G (9x300); [5400,5441) = taps

__global__ __launch_bounds__(256)
void ladmm_precompute(const float* __restrict__ A,
                      const float* __restrict__ alphap,
                      const float* __restrict__ gammap,
                      float* __restrict__ ws)
{
    __shared__ float As[MDIM*NCOL];
    __shared__ float Gs[MDIM*NCOL];
    __shared__ float karr[NCOL];
    __shared__ double Sd[MDIM*MDIM];
    __shared__ double Sinv[MDIM*MDIM];
    const int tid = threadIdx.x;
    const double al = (double)alphap[0];
    const double g  = (double)gammap[0];
    // C = (al+2g) I - g (P + P^T), circulant symmetric tridiagonal.
    // Cinv[d] = factor * (r^d + r^(n-d)),  r = smaller root of g r^2 - (al+2g) r + g = 0
    const double a    = al + 2.0*g;
    const double disc = sqrt(a*a - 4.0*g*g);
    const double r    = (a - disc) / (2.0*g);
    const double rn   = pow(r, (double)NCOL);
    const double factor = 1.0 / (g * (1.0/r - r) * (1.0 - rn));

    for (int d = tid; d < NCOL; d += blockDim.x) {
        int dd = (d < NCOL - d) ? d : NCOL - d;   // circular distance
        karr[d] = (float)(factor * (pow(r,(double)dd) + pow(r,(double)(NCOL-dd))));
    }
    for (int i = tid; i < MDIM*NCOL; i += blockDim.x) As[i] = A[i];
    __syncthreads();
    // G = A * Cinv  (9 x 300)
    for (int e = tid; e < MDIM*NCOL; e += blockDim.x) {
        int p = e / NCOL, j = e - p*NCOL;
        float s = 0.f;
        for (int k = 0; k < NCOL; ++k) {
            int d = j - k; if (d < 0) d += NCOL;
            s += As[p*NCOL+k] * karr[d];
        }
        Gs[e] = s;
        ws[e] = s;
    }
    __syncthreads();
    // S = I9 + G A^T  (9x9, double)
    if (tid < MDIM*MDIM) {
        int p = tid / MDIM, q = tid - p*MDIM;
        double s = (p == q) ? 1.0 : 0.0;
        for (int j = 0; j < NCOL; ++j)
            s += (double)Gs[p*NCOL+j] * (double)As[q*NCOL+j];
        Sd[tid] = s;
    }
    __syncthreads();
    if (tid == 0) {
        // invert 9x9 SPD via Gauss-Jordan in double (no pivoting needed for SPD)
        double Mm[MDIM][2*MDIM];
        for (int i2 = 0; i2 < MDIM; ++i2)
            for (int j2 = 0; j2 < 2*MDIM; ++j2)
                Mm[i2][j2] = (j2 < MDIM) ? Sd[i2*MDIM+j2] : ((j2-MDIM == i2) ? 1.0 : 0.0);
        for (int k = 0; k < MDIM; ++k) {
            double ip = 1.0 / Mm[k][k];
            for (int j2 = 0; j2 < 2*MDIM; ++j2) Mm[k][j2] *= ip;
            for (int i2 = 0; i2 < MDIM; ++i2) if (i2 != k) {
                double f = Mm[i2][k];
                for (int j2 = 0; j2 < 2*MDIM; ++j2) Mm[i2][j2] -= f * Mm[k][j2];
            }
        }
        for (int i2 = 0; i2 < MDIM; ++i2)
            for (int j2 = 0; j2 < MDIM; ++j2)
                Sinv[i2*MDIM+j2] = Mm[i2][MDIM+j2];
    }
    __syncthreads();
    // H = Sinv * G  (9 x 300)
    for (int e = tid; e < MDIM*NCOL; e += blockDim.x) {
        int q = e / NCOL, j = e - q*NCOL;
        double s = 0.0;
        for (int p = 0; p < MDIM; ++p)
            s += Sinv[q*MDIM+p] * (double)Gs[p*NCOL+j];
        ws[MDIM*NCOL + e] = (float)s;
    }
    // conv taps: taps[t] = Cinv[|t - DHALF|]
    for (int t = tid; t < NTAPS; t += blockDim.x) {
        int di = t - DHALF; if (di < 0) di = -di;
        ws[2*MDIM*NCOL + t] = (float)(factor * (pow(r,(double)di) + pow(r,(double)(NCOL-di))));
    }
}

__global__ __launch_bounds__(BLOCK)
void ladmm_main(const float* __restrict__ b,
                const float* __restrict__ x0,
                const float* __restrict__ A,
                const float* __restrict__ alphap,
                const float* __restrict__ gammap,
                const float* __restrict__ lamp,
                const float* __restrict__ ws,
                float* __restrict__ out)
{
    __shared__ float As[MDIM*NCOL];
    __shared__ float Gs[MDIM*NCOL];
    __shared__ float Hs[MDIM*NCOL];
    __shared__ float xbuf[WPB][NCOL + 8];               // [0] = x[NCOL-1] halo, [1..NCOL] = x
    __shared__ float rbuf[WPB][NCOL + 2*DHALF + 8];     // index DHALF + j for j in [-DHALF, NCOL+DHALF)

    const int tid  = threadIdx.x;
    const int lane = tid & 63;
    const int wv   = tid >> 6;

    const float al  = alphap[0];
    const float g   = gammap[0];
    const float lam = lamp[0];
    const float inv_al = 1.0f / al;
    const float inv_g  = 1.0f / g;
    const float thr = lam * inv_g;

    for (int i = tid; i < MDIM*NCOL; i += BLOCK) {
        As[i] = A[i];
        Gs[i] = ws[i];
        Hs[i] = ws[MDIM*NCOL + i];
    }
    float taps[NTAPS];
    #pragma unroll
    for (int t = 0; t < NTAPS; ++t) taps[t] = ws[2*MDIM*NCOL + t];  // uniform -> scalar loads
    __syncthreads();

    const bool act = (lane < 60);
    const int j0 = lane * 5;          // this lane owns columns j0..j0+4
    float* xb = xbuf[wv];
    float* rb = rbuf[wv];
    const int gwave = blockIdx.x * WPB + wv;

    for (int rr = 0; rr < RPW; ++rr) {
        const int row = gwave * RPW + rr;
        // stage x0 row (coalesced) into xb with wrap halo
        {
            const float* xr = x0 + (size_t)row * NCOL;
            for (int k = lane; k < NCOL; k += 64) {
                float v = xr[k];
                xb[1 + k] = v;
                if (k == NCOL - 1) xb[0] = v;
            }
        }
        // bA[j] = sum_p b[p] * A[p][j]  (b row is wave-uniform)
        float bA[5] = {0.f, 0.f, 0.f, 0.f, 0.f};
        {
            const float* brow = b + (size_t)row * MDIM;
            float bv[MDIM];
            #pragma unroll
            for (int p = 0; p < MDIM; ++p) bv[p] = brow[p];
            if (act) {
                #pragma unroll
                for (int p = 0; p < MDIM; ++p) {
                    #pragma unroll
                    for (int i = 0; i < 5; ++i)
                        bA[i] += bv[p] * As[p*NCOL + j0 + i];
                }
            }
        }
        float eta[5] = {0.f, 0.f, 0.f, 0.f, 0.f};
        float tau[5] = {0.f, 0.f, 0.f, 0.f, 0.f};
        float u[5], wq[5], y[5];
        __syncthreads();

        for (int it = 0; it < NITER; ++it) {
            if (act) {
                float xm = xb[j0];                 // x[j0-1] (circular)
                float xc[5];
                #pragma unroll
                for (int i = 0; i < 5; ++i) xc[i] = xb[1 + j0 + i];
                #pragma unroll
                for (int i = 0; i < 5; ++i) {
                    float xjm1 = (i == 0) ? xm : xc[i-1];
                    float xj = xc[i];
                    if (it > 0) {                  // dual updates from previous iteration
                        eta[i] += g  * (xjm1 - xj - u[i]);
                        tau[i] += al * (xj - wq[i]);
                    }
                    float v  = xjm1 - xj + eta[i] * inv_g;
                    float av = fabsf(v) - thr;
                    u[i]  = (av > 0.f) ? copysignf(av, v) : 0.f;
                    wq[i] = fmaxf(xj + tau[i] * inv_al, 0.f);
                    float resid = bA[i] + al*wq[i] - tau[i] + g*u[i] - eta[i];
                    int j = j0 + i;
                    rb[DHALF + j] = resid;
                    if (j < DHALF)        rb[DHALF + NCOL + j]   = resid;  // right halo
                    if (j >= NCOL - DHALF) rb[j - (NCOL - DHALF)] = resid; // left halo
                }
            }
            __syncthreads();
            float tpart[MDIM];
            #pragma unroll
            for (int p = 0; p < MDIM; ++p) tpart[p] = 0.f;
            if (act) {
                float win[5 + 2*DHALF];
                #pragma unroll
                for (int q = 0; q < 5 + 2*DHALF; ++q) win[q] = rb[j0 + q];
                #pragma unroll
                for (int i = 0; i < 5; ++i) y[i] = 0.f;
                // y = conv(resid) with geometric kernel (resid @ Cinv)
                #pragma unroll
                for (int t = 0; t < NTAPS; ++t) {
                    float kt = taps[t];
                    #pragma unroll
                    for (int i = 0; i < 5; ++i) y[i] += kt * win[i + t];
                }
                // partial t_p = sum_j resid[j] G[p][j] over this lane's columns
                #pragma unroll
                for (int p = 0; p < MDIM; ++p) {
                    float s = 0.f;
                    #pragma unroll
                    for (int i = 0; i < 5; ++i)
                        s += win[DHALF + i] * Gs[p*NCOL + j0 + i];
                    tpart[p] = s;
                }
            }
            // wave-wide butterfly reduce of the 9 projections
            #pragma unroll
            for (int p = 0; p < MDIM; ++p) {
                float s = tpart[p];
                s += __shfl_xor(s, 1);
                s += __shfl_xor(s, 2);
                s += __shfl_xor(s, 4);
                s += __shfl_xor(s, 8);
                s += __shfl_xor(s, 16);
                s += __shfl_xor(s, 32);
                tpart[p] = s;
            }
            if (act) {
                // x_new = conv - sum_p t_p H[p][:]   (Woodbury rank-9 correction)
                #pragma unroll
                for (int p = 0; p < MDIM; ++p) {
                    float tp = tpart[p];
                    #pragma unroll
                    for (int i = 0; i < 5; ++i)
                        y[i] -= tp * Hs[p*NCOL + j0 + i];
                }
                #pragma unroll
                for (int i = 0; i < 5; ++i) xb[1 + j0 + i] = y[i];
                if (j0 + 4 == NCOL - 1) xb[0] = y[4];   // refresh wrap halo
            }
            __syncthreads();
        }
        // write x (coalesced)
        {
            float* orow = out + (size_t)row * NCOL;
            for (int k = lane; k < NCOL; k += 64) orow[k] = xb[1 + k];
        }
        __syncthreads();
    }
}

extern "C" void kernel_launch(void* const* d_in, const int* in_sizes, int n_in,
                              void* d_out, int out_size, void* d_ws, size_t ws_size,
                              hipStream_t stream) {
    const float* b     = (const float*)d_in[0];
    // d_in[1] = target (unused, shape only)
    const float* x0    = (const float*)d_in[2];
    const float* A     = (const float*)d_in[3];
    const float* alpha = (const float*)d_in[4];
    const float* gamma = (const float*)d_in[5];
    const float* lam   = (const float*)d_in[6];
    float* out = (float*)d_out;
    float* ws  = (float*)d_ws;

    ladmm_precompute<<<dim3(1), dim3(256), 0, stream>>>(A, alpha, gamma, ws);
    ladmm_main<<<dim3(NBLOCKS), dim3(BLOCK), 0, stream>>>(b, x0, A, alpha, gamma, lam, ws, out);
}

// Round 2
// 768.986 us; speedup vs baseline: 1.0869x; 1.0869x over previous
//
#include <hip/hip_runtime.h>
#include <math.h>

#define NROW 65536
#define NCOL 300
#define MDIM 9
#define DHALF 16
#define NTAPS (2*DHALF+1)   // 33
#define NITER 5
#define BLOCK 256
#define WPB 4               // waves per block
#define RPW 8               // rows per wave
#define NBLOCKS (NROW / (WPB * RPW))   // 2048

// ws float layout: [0,2700) = G (9x300); [2700,5400) = H = Sinv*G (9x300); [5400,5400+NTAPS) = taps

// Wave-local LDS sync: lanes of one wave exchange via per-wave LDS buffers.
// s_waitcnt lgkmcnt(0) drains this wave's DS writes; asm memory clobber stops
// the compiler moving LDS accesses across it; sched_barrier pins scheduling.
#define WAVE_SYNC() do { \
    asm volatile("s_waitcnt lgkmcnt(0)" ::: "memory"); \
    __builtin_amdgcn_sched_barrier(0); \
} while (0)

__global__ __launch_bounds__(256)
void ladmm_precompute(const float* __restrict__ A,
                      const float* __restrict__ alphap,
                      const float* __restrict__ gammap,
                      float* __restrict__ ws)
{
    __shared__ float As[MDIM*NCOL];
    __shared__ float Gs[MDIM*NCOL];
    __shared__ float karr[NCOL];
    __shared__ double Sd[MDIM*MDIM];
    __shared__ double Sinv[MDIM*MDIM];
    const int tid = threadIdx.x;
    const double al = (double)alphap[0];
    const double g  = (double)gammap[0];
    // C = (al+2g) I - g (P + P^T), circulant symmetric tridiagonal.
    // Cinv[d] = factor * (r^d + r^(n-d)),  r = smaller root of g r^2 - (al+2g) r + g = 0
    const double a    = al + 2.0*g;
    const double disc = sqrt(a*a - 4.0*g*g);
    const double r    = (a - disc) / (2.0*g);
    const double rn   = pow(r, (double)NCOL);
    const double factor = 1.0 / (g * (1.0/r - r) * (1.0 - rn));

    for (int d = tid; d < NCOL; d += blockDim.x) {
        int dd = (d < NCOL - d) ? d : NCOL - d;   // circular distance
        karr[d] = (float)(factor * (pow(r,(double)dd) + pow(r,(double)(NCOL-dd))));
    }
    for (int i = tid; i < MDIM*NCOL; i += blockDim.x) As[i] = A[i];
    __syncthreads();
    // G = A * Cinv  (9 x 300)
    for (int e = tid; e < MDIM*NCOL; e += blockDim.x) {
        int p = e / NCOL, j = e - p*NCOL;
        float s = 0.f;
        for (int k = 0; k < NCOL; ++k) {
            int d = j - k; if (d < 0) d += NCOL;
            s += As[p*NCOL+k] * karr[d];
        }
        Gs[e] = s;
        ws[e] = s;
    }
    __syncthreads();
    // S = I9 + G A^T  (9x9, double)
    if (tid < MDIM*MDIM) {
        int p = tid / MDIM, q = tid - p*MDIM;
        double s = (p == q) ? 1.0 : 0.0;
        for (int j = 0; j < NCOL; ++j)
            s += (double)Gs[p*NCOL+j] * (double)As[q*NCOL+j];
        Sd[tid] = s;
    }
    __syncthreads();
    if (tid == 0) {
        // invert 9x9 SPD via Gauss-Jordan in double
        double Mm[MDIM][2*MDIM];
        for (int i2 = 0; i2 < MDIM; ++i2)
            for (int j2 = 0; j2 < 2*MDIM; ++j2)
                Mm[i2][j2] = (j2 < MDIM) ? Sd[i2*MDIM+j2] : ((j2-MDIM == i2) ? 1.0 : 0.0);
        for (int k = 0; k < MDIM; ++k) {
            double ip = 1.0 / Mm[k][k];
            for (int j2 = 0; j2 < 2*MDIM; ++j2) Mm[k][j2] *= ip;
            for (int i2 = 0; i2 < MDIM; ++i2) if (i2 != k) {
                double f = Mm[i2][k];
                for (int j2 = 0; j2 < 2*MDIM; ++j2) Mm[i2][j2] -= f * Mm[k][j2];
            }
        }
        for (int i2 = 0; i2 < MDIM; ++i2)
            for (int j2 = 0; j2 < MDIM; ++j2)
                Sinv[i2*MDIM+j2] = Mm[i2][MDIM+j2];
    }
    __syncthreads();
    // H = Sinv * G  (9 x 300)
    for (int e = tid; e < MDIM*NCOL; e += blockDim.x) {
        int q = e / NCOL, j = e - q*NCOL;
        double s = 0.0;
        for (int p = 0; p < MDIM; ++p)
            s += Sinv[q*MDIM+p] * (double)Gs[p*NCOL+j];
        ws[MDIM*NCOL + e] = (float)s;
    }
    // conv taps: taps[t] = Cinv[|t - DHALF|]
    for (int t = tid; t < NTAPS; t += blockDim.x) {
        int di = t - DHALF; if (di < 0) di = -di;
        ws[2*MDIM*NCOL + t] = (float)(factor * (pow(r,(double)di) + pow(r,(double)(NCOL-di))));
    }
}

__global__ __launch_bounds__(BLOCK, 5)
void ladmm_main(const float* __restrict__ b,
                const float* __restrict__ x0,
                const float* __restrict__ A,
                const float* __restrict__ alphap,
                const float* __restrict__ gammap,
                const float* __restrict__ lamp,
                const float* __restrict__ ws,
                float* __restrict__ out)
{
    __shared__ float Gs[MDIM*NCOL];
    __shared__ float Hs[MDIM*NCOL];
    __shared__ float xbuf[WPB][NCOL + 4];               // [0] = x[NCOL-1] halo, [1..NCOL] = x
    __shared__ float rbuf[WPB][NCOL + 2*DHALF + 4];     // index DHALF + j for j in [-DHALF, NCOL+DHALF)

    const int tid  = threadIdx.x;
    const int lane = tid & 63;
    const int wv   = tid >> 6;

    const float al  = alphap[0];
    const float g   = gammap[0];
    const float lam = lamp[0];
    const float inv_al = 1.0f / al;
    const float inv_g  = 1.0f / g;
    const float thr = lam * inv_g;

    for (int i = tid; i < MDIM*NCOL; i += BLOCK) {
        Gs[i] = ws[i];
        Hs[i] = ws[MDIM*NCOL + i];
    }
    float taps[NTAPS];
    #pragma unroll
    for (int t = 0; t < NTAPS; ++t) taps[t] = ws[2*MDIM*NCOL + t];  // uniform -> SGPR
    __syncthreads();   // one-time: tables visible to all waves; after this, waves are independent

    const bool act = (lane < 60);
    const int j0 = lane * 5;          // this lane owns columns j0..j0+4
    float* xb = xbuf[wv];
    float* rb = rbuf[wv];
    const int gwave = blockIdx.x * WPB + wv;

    for (int rr = 0; rr < RPW; ++rr) {
        const int row = gwave * RPW + rr;
        // stage x0 row (coalesced) into xb with wrap halo
        {
            const float* xr = x0 + (size_t)row * NCOL;
            for (int k = lane; k < NCOL; k += 64) {
                float v = xr[k];
                xb[1 + k] = v;
                if (k == NCOL - 1) xb[0] = v;
            }
        }
        // bA[j] = sum_p b[p] * A[p][j]   (A is L1-resident: 10.8 KB shared by all waves)
        float bA[5] = {0.f, 0.f, 0.f, 0.f, 0.f};
        {
            const float* brow = b + (size_t)row * MDIM;
            float bv[MDIM];
            #pragma unroll
            for (int p = 0; p < MDIM; ++p) bv[p] = brow[p];
            if (act) {
                #pragma unroll
                for (int p = 0; p < MDIM; ++p) {
                    #pragma unroll
                    for (int i = 0; i < 5; ++i)
                        bA[i] += bv[p] * A[p*NCOL + j0 + i];
                }
            }
        }
        float eta[5] = {0.f, 0.f, 0.f, 0.f, 0.f};
        float tau[5] = {0.f, 0.f, 0.f, 0.f, 0.f};
        float u[5], wq[5], y[5];
        WAVE_SYNC();   // x0 staging visible within the wave

        #pragma unroll
        for (int it = 0; it < NITER; ++it) {
            if (act) {
                float xm = xb[j0];                 // x[j0-1] (circular)
                float xc[5];
                #pragma unroll
                for (int i = 0; i < 5; ++i) xc[i] = xb[1 + j0 + i];
                #pragma unroll
                for (int i = 0; i < 5; ++i) {
                    float xjm1 = (i == 0) ? xm : xc[i-1];
                    float xj = xc[i];
                    if (it > 0) {                  // dual updates from previous iteration
                        eta[i] += g  * (xjm1 - xj - u[i]);
                        tau[i] += al * (xj - wq[i]);
                    }
                    float v  = xjm1 - xj + eta[i] * inv_g;
                    float av = fabsf(v) - thr;
                    u[i]  = (av > 0.f) ? copysignf(av, v) : 0.f;
                    wq[i] = fmaxf(xj + tau[i] * inv_al, 0.f);
                    float resid = bA[i] + al*wq[i] - tau[i] + g*u[i] - eta[i];
                    int j = j0 + i;
                    rb[DHALF + j] = resid;
                    if (j < DHALF)         rb[DHALF + NCOL + j]    = resid;  // right halo
                    if (j >= NCOL - DHALF) rb[j - (NCOL - DHALF)]  = resid;  // left halo
                }
            }
            WAVE_SYNC();   // resid + halos visible within the wave
            float tpart[MDIM];
            #pragma unroll
            for (int p = 0; p < MDIM; ++p) tpart[p] = 0.f;
            if (act) {
                float win[5 + 2*DHALF];
                #pragma unroll
                for (int q = 0; q < 5 + 2*DHALF; ++q) win[q] = rb[j0 + q];
                #pragma unroll
                for (int i = 0; i < 5; ++i) y[i] = 0.f;
                // y = conv(resid) with geometric kernel (resid @ Cinv)
                #pragma unroll
                for (int t = 0; t < NTAPS; ++t) {
                    float kt = taps[t];
                    #pragma unroll
                    for (int i = 0; i < 5; ++i) y[i] += kt * win[i + t];
                }
                // partial t_p = sum_j resid[j] G[p][j] over this lane's columns
                #pragma unroll
                for (int p = 0; p < MDIM; ++p) {
                    float s = 0.f;
                    #pragma unroll
                    for (int i = 0; i < 5; ++i)
                        s += win[DHALF + i] * Gs[p*NCOL + j0 + i];
                    tpart[p] = s;
                }
            }
            // wave-wide butterfly reduce of the 9 projections
            #pragma unroll
            for (int p = 0; p < MDIM; ++p) {
                float s = tpart[p];
                s += __shfl_xor(s, 1);
                s += __shfl_xor(s, 2);
                s += __shfl_xor(s, 4);
                s += __shfl_xor(s, 8);
                s += __shfl_xor(s, 16);
                s += __shfl_xor(s, 32);
                tpart[p] = s;
            }
            if (act) {
                // x_new = conv - sum_p t_p H[p][:]   (Woodbury rank-9 correction)
                #pragma unroll
                for (int p = 0; p < MDIM; ++p) {
                    float tp = tpart[p];
                    #pragma unroll
                    for (int i = 0; i < 5; ++i)
                        y[i] -= tp * Hs[p*NCOL + j0 + i];
                }
                #pragma unroll
                for (int i = 0; i < 5; ++i) xb[1 + j0 + i] = y[i];
                if (j0 + 4 == NCOL - 1) xb[0] = y[4];   // refresh wrap halo
            }
            WAVE_SYNC();   // new x visible within the wave
        }
        // write x (coalesced)
        {
            float* orow = out + (size_t)row * NCOL;
            for (int k = lane; k < NCOL; k += 64) orow[k] = xb[1 + k];
        }
    }
}

extern "C" void kernel_launch(void* const* d_in, const int* in_sizes, int n_in,
                              void* d_out, int out_size, void* d_ws, size_t ws_size,
                              hipStream_t stream) {
    const float* b     = (const float*)d_in[0];
    // d_in[1] = target (unused, shape only)
    const float* x0    = (const float*)d_in[2];
    const float* A     = (const float*)d_in[3];
    const float* alpha = (const float*)d_in[4];
    const float* gamma = (const float*)d_in[5];
    const float* lam   = (const float*)d_in[6];
    float* out = (float*)d_out;
    float* ws  = (float*)d_ws;

    ladmm_precompute<<<dim3(1), dim3(256), 0, stream>>>(A, alpha, gamma, ws);
    ladmm_main<<<dim3(NBLOCKS), dim3(BLOCK), 0, stream>>>(b, x0, A, alpha, gamma, lam, ws, out);
}

// Round 3
// 621.797 us; speedup vs baseline: 1.3442x; 1.2367x over previous
//
#include <hip/hip_runtime.h>
#include <math.h>

#define NROW 65536
#define NCOL 300
#define MDIM 9
#define DHALF 16
#define NTAPS (2*DHALF+1)   // 33
#define NITER 5
#define BLOCK 256
#define WPB 4               // waves per block
#define RPW 8               // rows per wave
#define NBLOCKS (NROW / (WPB * RPW))   // 2048

// ws float layout: [0,2700) = G (9x300); [2700,5400) = H = Sinv*G (9x300); [5400,5400+NTAPS) = taps

// Wave-local LDS sync: lanes of one wave exchange via per-wave LDS buffers.
#define WAVE_SYNC() do { \
    asm volatile("s_waitcnt lgkmcnt(0)" ::: "memory"); \
    __builtin_amdgcn_sched_barrier(0); \
} while (0)

// Butterfly stage via DPP (VALU pipe, not LDS): sum-reducing permutation
template<int CTRL>
__device__ __forceinline__ float dpp_xadd(float s) {
    int v = __builtin_amdgcn_update_dpp(0, __float_as_int(s), CTRL, 0xF, 0xF, true);
    return s + __int_as_float(v);
}

__global__ __launch_bounds__(256)
void ladmm_precompute(const float* __restrict__ A,
                      const float* __restrict__ alphap,
                      const float* __restrict__ gammap,
                      float* __restrict__ ws)
{
    __shared__ float As[MDIM*NCOL];
    __shared__ float Gs[MDIM*NCOL];
    __shared__ float karr[NCOL];
    __shared__ double Sd[MDIM*MDIM];
    __shared__ double Sinv[MDIM*MDIM];
    const int tid = threadIdx.x;
    const double al = (double)alphap[0];
    const double g  = (double)gammap[0];
    // C = (al+2g) I - g (P + P^T), circulant symmetric tridiagonal.
    // Cinv[d] = factor * (r^d + r^(n-d)),  r = smaller root of g r^2 - (al+2g) r + g = 0
    const double a    = al + 2.0*g;
    const double disc = sqrt(a*a - 4.0*g*g);
    const double r    = (a - disc) / (2.0*g);
    const double rn   = pow(r, (double)NCOL);
    const double factor = 1.0 / (g * (1.0/r - r) * (1.0 - rn));

    for (int d = tid; d < NCOL; d += blockDim.x) {
        int dd = (d < NCOL - d) ? d : NCOL - d;   // circular distance
        karr[d] = (float)(factor * (pow(r,(double)dd) + pow(r,(double)(NCOL-dd))));
    }
    for (int i = tid; i < MDIM*NCOL; i += blockDim.x) As[i] = A[i];
    __syncthreads();
    // G = A * Cinv  (9 x 300)
    for (int e = tid; e < MDIM*NCOL; e += blockDim.x) {
        int p = e / NCOL, j = e - p*NCOL;
        float s = 0.f;
        for (int k = 0; k < NCOL; ++k) {
            int d = j - k; if (d < 0) d += NCOL;
            s += As[p*NCOL+k] * karr[d];
        }
        Gs[e] = s;
        ws[e] = s;
    }
    __syncthreads();
    // S = I9 + G A^T  (9x9, double)
    if (tid < MDIM*MDIM) {
        int p = tid / MDIM, q = tid - p*MDIM;
        double s = (p == q) ? 1.0 : 0.0;
        for (int j = 0; j < NCOL; ++j)
            s += (double)Gs[p*NCOL+j] * (double)As[q*NCOL+j];
        Sd[tid] = s;
    }
    __syncthreads();
    if (tid == 0) {
        double Mm[MDIM][2*MDIM];
        for (int i2 = 0; i2 < MDIM; ++i2)
            for (int j2 = 0; j2 < 2*MDIM; ++j2)
                Mm[i2][j2] = (j2 < MDIM) ? Sd[i2*MDIM+j2] : ((j2-MDIM == i2) ? 1.0 : 0.0);
        for (int k = 0; k < MDIM; ++k) {
            double ip = 1.0 / Mm[k][k];
            for (int j2 = 0; j2 < 2*MDIM; ++j2) Mm[k][j2] *= ip;
            for (int i2 = 0; i2 < MDIM; ++i2) if (i2 != k) {
                double f = Mm[i2][k];
                for (int j2 = 0; j2 < 2*MDIM; ++j2) Mm[i2][j2] -= f * Mm[k][j2];
            }
        }
        for (int i2 = 0; i2 < MDIM; ++i2)
            for (int j2 = 0; j2 < MDIM; ++j2)
                Sinv[i2*MDIM+j2] = Mm[i2][MDIM+j2];
    }
    __syncthreads();
    // H = Sinv * G  (9 x 300)
    for (int e = tid; e < MDIM*NCOL; e += blockDim.x) {
        int q = e / NCOL, j = e - q*NCOL;
        double s = 0.0;
        for (int p = 0; p < MDIM; ++p)
            s += Sinv[q*MDIM+p] * (double)Gs[p*NCOL+j];
        ws[MDIM*NCOL + e] = (float)s;
    }
    // conv taps: taps[t] = Cinv[|t - DHALF|]
    for (int t = tid; t < NTAPS; t += blockDim.x) {
        int di = t - DHALF; if (di < 0) di = -di;
        ws[2*MDIM*NCOL + t] = (float)(factor * (pow(r,(double)di) + pow(r,(double)(NCOL-di))));
    }
}

__global__ __launch_bounds__(BLOCK)
void ladmm_main(const float* __restrict__ b,
                const float* __restrict__ x0,
                const float* __restrict__ A,
                const float* __restrict__ alphap,
                const float* __restrict__ gammap,
                const float* __restrict__ lamp,
                const float* __restrict__ ws,
                float* __restrict__ out)
{
    __shared__ float Gs[MDIM*NCOL];
    __shared__ float rbuf[WPB][NCOL + 2*DHALF + 4];   // index DHALF + j, j in [-DHALF, NCOL+DHALF)

    const int tid  = threadIdx.x;
    const int lane = tid & 63;
    const int wv   = tid >> 6;

    const float al  = alphap[0];
    const float g   = gammap[0];
    const float lam = lamp[0];
    const float inv_al = 1.0f / al;
    const float inv_g  = 1.0f / g;
    const float thr = lam * inv_g;

    const float* __restrict__ Hg = ws + MDIM*NCOL;    // H stays in global: L1-resident 10.8 KB

    for (int i = tid; i < MDIM*NCOL; i += BLOCK) Gs[i] = ws[i];
    // taps -> SGPRs (wave-uniform), forced via readfirstlane
    float taps[NTAPS];
    #pragma unroll
    for (int t = 0; t < NTAPS; ++t)
        taps[t] = __int_as_float(__builtin_amdgcn_readfirstlane(__float_as_int(ws[2*MDIM*NCOL + t])));
    __syncthreads();   // one-time: Gs visible to all waves; afterwards waves are independent

    const bool act = (lane < 60);
    const int j0 = lane * 5;                 // this lane owns columns j0..j0+4
    const int lprev = (lane == 0) ? 59 : lane - 1;   // circular left neighbor (among 60 active)
    float* rb = rbuf[wv];
    const int gwave = blockIdx.x * WPB + wv;

    for (int rr = 0; rr < RPW; ++rr) {
        const int row = gwave * RPW + rr;
        // x kept fully in registers: xc[5] per lane + xm = x[j0-1] via shuffle
        float xc[5] = {0.f,0.f,0.f,0.f,0.f};
        if (act) {
            const float* xr = x0 + (size_t)row * NCOL + j0;
            #pragma unroll
            for (int i = 0; i < 5; ++i) xc[i] = xr[i];
        }
        float xm = __shfl(xc[4], lprev);

        // bA[j] = sum_p b[p] * A[p][j]   (b row wave-uniform -> s_loads; A is L1-hot)
        float bA[5] = {0.f,0.f,0.f,0.f,0.f};
        {
            const float* brow = b + (size_t)row * MDIM;
            #pragma unroll
            for (int p = 0; p < MDIM; ++p) {
                float bv = brow[p];
                if (act) {
                    #pragma unroll
                    for (int i = 0; i < 5; ++i)
                        bA[i] += bv * A[p*NCOL + j0 + i];
                }
            }
        }
        float eta[5] = {0.f,0.f,0.f,0.f,0.f};
        float tau[5] = {0.f,0.f,0.f,0.f,0.f};
        float u[5], wq[5], y[5], rsd[5];

        #pragma unroll
        for (int it = 0; it < NITER; ++it) {
            if (act) {
                #pragma unroll
                for (int i = 0; i < 5; ++i) {
                    float xjm1 = (i == 0) ? xm : xc[i-1];
                    float xj = xc[i];
                    if (it > 0) {                  // dual updates from previous iteration
                        eta[i] += g  * (xjm1 - xj - u[i]);
                        tau[i] += al * (xj - wq[i]);
                    }
                    float v  = xjm1 - xj + eta[i] * inv_g;
                    float av = fabsf(v) - thr;
                    u[i]  = (av > 0.f) ? copysignf(av, v) : 0.f;
                    wq[i] = fmaxf(xj + tau[i] * inv_al, 0.f);
                    float resid = bA[i] + al*wq[i] - tau[i] + g*u[i] - eta[i];
                    rsd[i] = resid;
                    int j = j0 + i;
                    rb[DHALF + j] = resid;
                    if (j < DHALF)         rb[DHALF + NCOL + j]   = resid;  // right halo
                    if (j >= NCOL - DHALF) rb[j - (NCOL - DHALF)] = resid;  // left halo
                }
            }
            WAVE_SYNC();   // resid + halos visible within the wave

            // rank-9 projection partials from own registers (no LDS re-read)
            float tpart[MDIM];
            #pragma unroll
            for (int p = 0; p < MDIM; ++p) tpart[p] = 0.f;
            if (act) {
                #pragma unroll
                for (int p = 0; p < MDIM; ++p) {
                    float s = 0.f;
                    #pragma unroll
                    for (int i = 0; i < 5; ++i)
                        s += rsd[i] * Gs[p*NCOL + j0 + i];
                    tpart[p] = s;
                }
            }
            // wave reduce: DPP for stages 1/2/4/8 (VALU), shfl for 16/32
            #pragma unroll
            for (int p = 0; p < MDIM; ++p) {
                float s = tpart[p];
                s = dpp_xadd<0xB1>(s);    // quad_perm [1,0,3,2]  : xor1
                s = dpp_xadd<0x4E>(s);    // quad_perm [2,3,0,1]  : xor2
                s = dpp_xadd<0x141>(s);   // row_half_mirror      : sum over 8
                s = dpp_xadd<0x140>(s);   // row_mirror           : sum over 16
                s += __shfl_xor(s, 16);
                s += __shfl_xor(s, 32);
                tpart[p] = s;
            }

            if (act) {
                // streaming conv: load each rb element once, feed <=5 FMAs (taps in SGPRs)
                #pragma unroll
                for (int i = 0; i < 5; ++i) y[i] = 0.f;
                #pragma unroll
                for (int q = 0; q < 5 + 2*DHALF; ++q) {
                    float wv_ = rb[j0 + q];
                    #pragma unroll
                    for (int i = 0; i < 5; ++i) {
                        int t = q - i;
                        if (t >= 0 && t < NTAPS) y[i] += taps[t] * wv_;
                    }
                }
                // Woodbury rank-9 correction, H from global (L1 pipe, parallel to LDS)
                #pragma unroll
                for (int p = 0; p < MDIM; ++p) {
                    float tp = tpart[p];
                    #pragma unroll
                    for (int i = 0; i < 5; ++i)
                        y[i] -= tp * Hg[p*NCOL + j0 + i];
                }
            }
            // new x: registers + one shuffle for the circular neighbor
            xm = __shfl(y[4], lprev);
            #pragma unroll
            for (int i = 0; i < 5; ++i) xc[i] = y[i];
        }
        // write x directly from registers (wave covers 1200 contiguous bytes)
        if (act) {
            float* orow = out + (size_t)row * NCOL + j0;
            #pragma unroll
            for (int i = 0; i < 5; ++i) orow[i] = xc[i];
        }
    }
}

extern "C" void kernel_launch(void* const* d_in, const int* in_sizes, int n_in,
                              void* d_out, int out_size, void* d_ws, size_t ws_size,
                              hipStream_t stream) {
    const float* b     = (const float*)d_in[0];
    // d_in[1] = target (unused, shape only)
    const float* x0    = (const float*)d_in[2];
    const float* A     = (const float*)d_in[3];
    const float* alpha = (const float*)d_in[4];
    const float* gamma = (const float*)d_in[5];
    const float* lam   = (const float*)d_in[6];
    float* out = (float*)d_out;
    float* ws  = (float*)d_ws;

    ladmm_precompute<<<dim3(1), dim3(256), 0, stream>>>(A, alpha, gamma, ws);
    ladmm_main<<<dim3(NBLOCKS), dim3(BLOCK), 0, stream>>>(b, x0, A, alpha, gamma, lam, ws, out);
}

// Round 4
// 454.093 us; speedup vs baseline: 1.8407x; 1.3693x over previous
//
#include <hip/hip_runtime.h>
#include <math.h>

#define NROW 65536
#define NCOL 300
#define MDIM 9
#define NITER 5
#define BLOCK 256
#define WPB 4               // waves per block
#define RPW 8               // rows per wave
#define NBLOCKS (NROW / (WPB * RPW))   // 2048

// ws float layout: [0,2700) = G (9x300); [2700,5400) = H = Sinv*G (9x300)

// DPP sum step: s += dpp_perm(s), invalid sources contribute 0 (old=0, bound_ctrl)
template<int CTRL>
__device__ __forceinline__ float dpp_fadd(float s) {
    int v = __builtin_amdgcn_update_dpp(0, __float_as_int(s), CTRL, 0xF, 0xF, true);
    return s + __int_as_float(v);
}
__device__ __forceinline__ float readlane_f(float v, int l) {
    return __int_as_float(__builtin_amdgcn_readlane(__float_as_int(v), l));
}
__device__ __forceinline__ float sgpr_f(float v) {
    return __int_as_float(__builtin_amdgcn_readfirstlane(__float_as_int(v)));
}

__global__ __launch_bounds__(256)
void ladmm_precompute(const float* __restrict__ A,
                      const float* __restrict__ alphap,
                      const float* __restrict__ gammap,
                      float* __restrict__ ws)
{
    __shared__ float As[MDIM*NCOL];
    __shared__ float Gs[MDIM*NCOL];
    __shared__ float karr[NCOL];
    __shared__ double Sd[MDIM*MDIM];
    __shared__ double Sinv[MDIM*MDIM];
    const int tid = threadIdx.x;
    const double al = (double)alphap[0];
    const double g  = (double)gammap[0];
    // C = (al+2g) I - g (P + P^T): circulant symmetric tridiagonal.
    // Cinv[d] = factor * (r^d + r^(n-d)),  r = smaller root of g r^2 - (al+2g) r + g = 0
    const double a    = al + 2.0*g;
    const double disc = sqrt(a*a - 4.0*g*g);
    const double r    = (2.0*g) / (a + disc);
    const double rn   = pow(r, (double)NCOL);
    const double factor = 1.0 / (g * (1.0/r - r) * (1.0 - rn));

    for (int d = tid; d < NCOL; d += blockDim.x) {
        int dd = (d < NCOL - d) ? d : NCOL - d;   // circular distance
        karr[d] = (float)(factor * (pow(r,(double)dd) + pow(r,(double)(NCOL-dd))));
    }
    for (int i = tid; i < MDIM*NCOL; i += blockDim.x) As[i] = A[i];
    __syncthreads();
    // G = A * Cinv  (9 x 300)
    for (int e = tid; e < MDIM*NCOL; e += blockDim.x) {
        int p = e / NCOL, j = e - p*NCOL;
        float s = 0.f;
        for (int k = 0; k < NCOL; ++k) {
            int d = j - k; if (d < 0) d += NCOL;
            s += As[p*NCOL+k] * karr[d];
        }
        Gs[e] = s;
        ws[e] = s;
    }
    __syncthreads();
    // S = I9 + G A^T  (9x9, double)
    if (tid < MDIM*MDIM) {
        int p = tid / MDIM, q = tid - p*MDIM;
        double s = (p == q) ? 1.0 : 0.0;
        for (int j = 0; j < NCOL; ++j)
            s += (double)Gs[p*NCOL+j] * (double)As[q*NCOL+j];
        Sd[tid] = s;
    }
    __syncthreads();
    if (tid == 0) {
        double Mm[MDIM][2*MDIM];
        for (int i2 = 0; i2 < MDIM; ++i2)
            for (int j2 = 0; j2 < 2*MDIM; ++j2)
                Mm[i2][j2] = (j2 < MDIM) ? Sd[i2*MDIM+j2] : ((j2-MDIM == i2) ? 1.0 : 0.0);
        for (int k = 0; k < MDIM; ++k) {
            double ip = 1.0 / Mm[k][k];
            for (int j2 = 0; j2 < 2*MDIM; ++j2) Mm[k][j2] *= ip;
            for (int i2 = 0; i2 < MDIM; ++i2) if (i2 != k) {
                double f = Mm[i2][k];
                for (int j2 = 0; j2 < 2*MDIM; ++j2) Mm[i2][j2] -= f * Mm[k][j2];
            }
        }
        for (int i2 = 0; i2 < MDIM; ++i2)
            for (int j2 = 0; j2 < MDIM; ++j2)
                Sinv[i2*MDIM+j2] = Mm[i2][MDIM+j2];
    }
    __syncthreads();
    // H = Sinv * G  (9 x 300)
    for (int e = tid; e < MDIM*NCOL; e += blockDim.x) {
        int q = e / NCOL, j = e - q*NCOL;
        double s = 0.0;
        for (int p = 0; p < MDIM; ++p)
            s += Sinv[q*MDIM+p] * (double)Gs[p*NCOL+j];
        ws[MDIM*NCOL + e] = (float)s;
    }
}

__global__ __launch_bounds__(BLOCK)
void ladmm_main(const float* __restrict__ b,
                const float* __restrict__ x0,
                const float* __restrict__ A,
                const float* __restrict__ alphap,
                const float* __restrict__ gammap,
                const float* __restrict__ lamp,
                const float* __restrict__ ws,
                float* __restrict__ out)
{
    const int tid  = threadIdx.x;
    const int lane = tid & 63;
    const int wv   = tid >> 6;

    const float al  = alphap[0];
    const float g   = gammap[0];
    const float lam = lamp[0];
    const float inv_al = 1.0f / al;
    const float inv_g  = 1.0f / g;
    const float thr = lam * inv_g;

    // geometric-kernel constants (uniform -> SGPR)
    const float aa   = al + 2.f*g;
    const float disc = sqrtf(aa*aa - 4.f*g*g);
    const float r    = sgpr_f((2.f*g) / (aa + disc));   // = 0.5 for these params
    const float q    = sgpr_f(r*r*r*r*r);               // ratio per lane-block of 5
    const float invq = sgpr_f(1.f / q);
    const float rn   = powf(r, (float)NCOL);
    const float factor = sgpr_f(1.f / (g * (1.f/r - r) * (1.f - rn)));
    const float r2 = sgpr_f(r*r), r3 = sgpr_f(r*r*r), r4 = sgpr_f(r*r*r*r);

    const bool act = (lane < 60);
    const int  j0  = lane * 5;                     // owned columns j0..j0+4
    const int  lprev = (lane == 0) ? 59 : lane - 1;

    // gated Hillis-Steele weights (scan window 8 lanes; q^8 = 2^-40 -> exact enough)
    const float q2 = q*q, q4 = q2*q2;
    const float wf1 = (lane>=1)?q:0.f, wf2=(lane>=2)?q2:0.f, wf4=(lane>=4)?q4:0.f;
    const float wb1 = (lane<=62)?q:0.f, wb2=(lane<=61)?q2:0.f, wb4=(lane<=59)?q4:0.f;
    // circular-wrap weights: r^{j0+1} (forward), r^{296-j0} (backward)
    const float vwF = powf(r, (float)(j0 + 1));
    const float vwB = act ? powf(r, (float)(296 - j0)) : 0.f;

    // G,H lane-slices cached in registers: zero per-iteration table traffic
    float Greg[MDIM][5], Hreg[MDIM][5];
    #pragma unroll
    for (int p = 0; p < MDIM; ++p) {
        #pragma unroll
        for (int i = 0; i < 5; ++i) {
            int idx = p*NCOL + (act ? j0 + i : 0);
            Greg[p][i] = act ? ws[idx] : 0.f;
            Hreg[p][i] = act ? ws[MDIM*NCOL + idx] : 0.f;
        }
    }

    const int gwave = blockIdx.x * WPB + wv;
    for (int rr = 0; rr < RPW; ++rr) {
        const int row = gwave * RPW + rr;
        float xc[5];
        {
            const float* xr = x0 + (size_t)row * NCOL + j0;
            #pragma unroll
            for (int i = 0; i < 5; ++i) xc[i] = act ? xr[i] : 0.f;
        }
        float xm = __shfl(xc[4], lprev);           // x[j0-1] circular

        float bA[5] = {0.f,0.f,0.f,0.f,0.f};
        {
            const float* brow = b + (size_t)row * MDIM;
            #pragma unroll
            for (int p = 0; p < MDIM; ++p) {
                float bv = brow[p];
                if (act) {
                    #pragma unroll
                    for (int i = 0; i < 5; ++i)
                        bA[i] += bv * A[p*NCOL + j0 + i];
                }
            }
        }
        float eta[5] = {0.f,0.f,0.f,0.f,0.f};
        float tau[5] = {0.f,0.f,0.f,0.f,0.f};
        float u[5], wq[5];

        #pragma unroll
        for (int it = 0; it < NITER; ++it) {
            float rsd[5];
            if (act) {
                #pragma unroll
                for (int i = 0; i < 5; ++i) {
                    float xjm1 = (i == 0) ? xm : xc[i-1];
                    float xj = xc[i];
                    float dx = xjm1 - xj;
                    if (it > 0) {                  // dual updates from previous iteration
                        eta[i] += g  * (dx - u[i]);
                        tau[i] += al * (xj - wq[i]);
                    }
                    float v  = dx + eta[i] * inv_g;
                    float av = fabsf(v) - thr;
                    u[i]  = (av > 0.f) ? copysignf(av, v) : 0.f;
                    wq[i] = fmaxf(xj + tau[i] * inv_al, 0.f);
                    rsd[i] = bA[i] + al*wq[i] - tau[i] + g*u[i] - eta[i];
                }
            } else {
                #pragma unroll
                for (int i = 0; i < 5; ++i) rsd[i] = 0.f;
            }

            // ---- resid @ Cinv via two geometric scans (exact) ----
            // forward: L_j = rsd_j + r*L_{j-1}
            float l0 = rsd[0];
            float l1 = fmaf(r, l0, rsd[1]);
            float l2 = fmaf(r, l1, rsd[2]);
            float l3 = fmaf(r, l2, rsd[3]);
            float l4 = fmaf(r, l3, rsd[4]);
            float S = l4, P = S;
            P = fmaf(wf1, __shfl_up(P, 1), P);
            P = fmaf(wf2, __shfl_up(P, 2), P);
            P = fmaf(wf4, __shfl_up(P, 4), P);
            float E    = (P - S) * invq;           // exclusive prefix
            float Ltot = readlane_f(P, 59);        // L_{n-1} (wrap source)
            // backward: R_j = rsd_j + r*R_{j+1}
            float m4 = rsd[4];
            float m3 = fmaf(r, m4, rsd[3]);
            float m2 = fmaf(r, m3, rsd[2]);
            float m1 = fmaf(r, m2, rsd[1]);
            float m0 = fmaf(r, m1, rsd[0]);
            float T = m0, Qs = T;
            Qs = fmaf(wb1, __shfl_down(Qs, 1), Qs);
            Qs = fmaf(wb2, __shfl_down(Qs, 2), Qs);
            Qs = fmaf(wb4, __shfl_down(Qs, 4), Qs);
            float Ep   = (Qs - T) * invq;
            float Atot = readlane_f(Qs, 0);        // R_0 (wrap source)

            float wF = vwF * Ltot;
            float wB = vwB * Atot;
            float y[5];
            // F_i = l_i + r^{i+1} E + wF r^i ;  B_i = m_i + r^{5-i} Ep + wB r^{4-i}
            y[0] = (l0 + r *E + wF   ) + (m0 + q *Ep + wB*r4) - rsd[0];
            y[1] = (l1 + r2*E + wF*r ) + (m1 + r4*Ep + wB*r3) - rsd[1];
            y[2] = (l2 + r3*E + wF*r2) + (m2 + r3*Ep + wB*r2) - rsd[2];
            y[3] = (l3 + r4*E + wF*r3) + (m3 + r2*Ep + wB*r ) - rsd[3];
            y[4] = (l4 + q *E + wF*r4) + (m4 + r *Ep + wB   ) - rsd[4];
            #pragma unroll
            for (int i = 0; i < 5; ++i) y[i] *= factor;

            // ---- rank-9 Woodbury correction; DPP all-reduce -> SGPR broadcast ----
            #pragma unroll
            for (int p = 0; p < MDIM; ++p) {
                float s =        rsd[0] * Greg[p][0];
                s = fmaf(rsd[1], Greg[p][1], s);
                s = fmaf(rsd[2], Greg[p][2], s);
                s = fmaf(rsd[3], Greg[p][3], s);
                s = fmaf(rsd[4], Greg[p][4], s);
                s = dpp_fadd<0x111>(s);   // row_shr:1
                s = dpp_fadd<0x112>(s);   // row_shr:2
                s = dpp_fadd<0x114>(s);   // row_shr:4
                s = dpp_fadd<0x118>(s);   // row_shr:8  -> lane 15 mod 16 has row sum
                s = dpp_fadd<0x142>(s);   // row_bcast15
                s = dpp_fadd<0x143>(s);   // row_bcast31 -> lane 63 has full sum
                float tp = readlane_f(s, 63);      // SGPR broadcast
                #pragma unroll
                for (int i = 0; i < 5; ++i)
                    y[i] = fmaf(-tp, Hreg[p][i], y[i]);
            }

            xm = __shfl(y[4], lprev);
            #pragma unroll
            for (int i = 0; i < 5; ++i) xc[i] = y[i];
        }

        if (act) {
            float* orow = out + (size_t)row * NCOL + j0;
            #pragma unroll
            for (int i = 0; i < 5; ++i) orow[i] = xc[i];
        }
    }
}

extern "C" void kernel_launch(void* const* d_in, const int* in_sizes, int n_in,
                              void* d_out, int out_size, void* d_ws, size_t ws_size,
                              hipStream_t stream) {
    const float* b     = (const float*)d_in[0];
    // d_in[1] = target (unused, shape only)
    const float* x0    = (const float*)d_in[2];
    const float* A     = (const float*)d_in[3];
    const float* alpha = (const float*)d_in[4];
    const float* gamma = (const float*)d_in[5];
    const float* lam   = (const float*)d_in[6];
    float* out = (float*)d_out;
    float* ws  = (float*)d_ws;

    ladmm_precompute<<<dim3(1), dim3(256), 0, stream>>>(A, alpha, gamma, ws);
    ladmm_main<<<dim3(NBLOCKS), dim3(BLOCK), 0, stream>>>(b, x0, A, alpha, gamma, lam, ws, out);
}

// Round 5
// 415.775 us; speedup vs baseline: 2.0103x; 1.0922x over previous
//
#include <hip/hip_runtime.h>
#include <math.h>

#define NROW 65536
#define NCOL 300
#define MDIM 9
#define NITER 5
#define BLOCK 256
#define WPB 4               // waves per block
#define RPW 8               // rows per wave
#define NBLOCKS (NROW / (WPB * RPW))   // 2048 -> 8192 waves = exactly full residency

// ws float layout: [0,2700) = G (9x300 row-major); [2700, 2700+3240) = H padded [9][60][6]
#define WS_H  (MDIM*NCOL)
#define HPAD  (MDIM*60*6)   // 3240 floats = 12.96 KB

// DPP sum step: s += dpp_perm(s), invalid sources contribute 0 (old=0, bound_ctrl)
template<int CTRL>
__device__ __forceinline__ float dpp_fadd(float s) {
    int v = __builtin_amdgcn_update_dpp(0, __float_as_int(s), CTRL, 0xF, 0xF, true);
    return s + __int_as_float(v);
}
__device__ __forceinline__ float readlane_f(float v, int l) {
    return __int_as_float(__builtin_amdgcn_readlane(__float_as_int(v), l));
}
__device__ __forceinline__ float sgpr_f(float v) {
    return __int_as_float(__builtin_amdgcn_readfirstlane(__float_as_int(v)));
}

// ---------- precompute, stage 1 (grid-parallel): G = A * Cinv ----------
__global__ __launch_bounds__(256)
void ladmm_pre_g(const float* __restrict__ A,
                 const float* __restrict__ alphap,
                 const float* __restrict__ gammap,
                 float* __restrict__ ws)
{
    __shared__ float As[MDIM*NCOL];
    __shared__ float karr[NCOL];
    const int tid = threadIdx.x;
    const double al = (double)alphap[0];
    const double g  = (double)gammap[0];
    const double a    = al + 2.0*g;
    const double disc = sqrt(a*a - 4.0*g*g);
    const double r    = (2.0*g) / (a + disc);
    const double rn   = pow(r, (double)NCOL);
    const double factor = 1.0 / (g * (1.0/r - r) * (1.0 - rn));

    for (int d = tid; d < NCOL; d += 256) {
        int dd = (d < NCOL - d) ? d : NCOL - d;
        karr[d] = (float)(factor * (pow(r,(double)dd) + pow(r,(double)(NCOL-dd))));
    }
    for (int i = tid; i < MDIM*NCOL; i += 256) As[i] = A[i];
    __syncthreads();
    const int e = blockIdx.x * 256 + tid;
    if (e < MDIM*NCOL) {
        const int p = e / NCOL, j = e - p*NCOL;
        float s = 0.f;
        for (int k = 0; k < NCOL; ++k) {
            int d = j - k; if (d < 0) d += NCOL;
            s += As[p*NCOL+k] * karr[d];
        }
        ws[e] = s;
    }
}

// ---------- precompute, stage 2 (1 block, tiny): S, S^-1, H (padded) ----------
__global__ __launch_bounds__(256)
void ladmm_pre_h(const float* __restrict__ A,
                 float* __restrict__ ws)
{
    __shared__ double Sd[MDIM*MDIM];
    __shared__ double Sinv[MDIM*MDIM];
    const int tid = threadIdx.x;
    // S = I9 + G A^T  (symmetric)
    if (tid < MDIM*MDIM) {
        int p = tid / MDIM, q = tid - p*MDIM;
        double s = (p == q) ? 1.0 : 0.0;
        for (int j = 0; j < NCOL; ++j)
            s += (double)ws[p*NCOL+j] * (double)A[q*NCOL+j];
        Sd[tid] = s;
    }
    __syncthreads();
    if (tid == 0) {
        double Mm[MDIM][2*MDIM];
        for (int i2 = 0; i2 < MDIM; ++i2)
            for (int j2 = 0; j2 < 2*MDIM; ++j2)
                Mm[i2][j2] = (j2 < MDIM) ? Sd[i2*MDIM+j2] : ((j2-MDIM == i2) ? 1.0 : 0.0);
        for (int k = 0; k < MDIM; ++k) {
            double ip = 1.0 / Mm[k][k];
            for (int j2 = 0; j2 < 2*MDIM; ++j2) Mm[k][j2] *= ip;
            for (int i2 = 0; i2 < MDIM; ++i2) if (i2 != k) {
                double f = Mm[i2][k];
                for (int j2 = 0; j2 < 2*MDIM; ++j2) Mm[i2][j2] -= f * Mm[k][j2];
            }
        }
        for (int i2 = 0; i2 < MDIM; ++i2)
            for (int j2 = 0; j2 < MDIM; ++j2)
                Sinv[i2*MDIM+j2] = Mm[i2][MDIM+j2];
    }
    __syncthreads();
    // H = Sinv * G, written in padded [9][60][6] layout (lane stride 24 B -> b64-aligned)
    for (int e = tid; e < MDIM*NCOL; e += 256) {
        const int p = e / NCOL, j = e - p*NCOL;
        double s = 0.0;
        for (int q = 0; q < MDIM; ++q)
            s += Sinv[p*MDIM+q] * (double)ws[q*NCOL+j];
        const int l = j / 5, i = j - l*5;
        ws[WS_H + (p*60 + l)*6 + i] = (float)s;
    }
}

// ---------- main ----------
__global__ __launch_bounds__(BLOCK)
void ladmm_main(const float* __restrict__ b,
                const float* __restrict__ x0,
                const float* __restrict__ A,
                const float* __restrict__ alphap,
                const float* __restrict__ gammap,
                const float* __restrict__ lamp,
                const float* __restrict__ ws,
                float* __restrict__ out)
{
    __shared__ float Hs[HPAD];   // 12.96 KB: H padded [9][60][6]

    const int tid  = threadIdx.x;
    const int lane = tid & 63;
    const int wv   = tid >> 6;

    const float al  = alphap[0];
    const float g   = gammap[0];
    const float lam = lamp[0];
    const float inv_al = 1.0f / al;
    const float inv_g  = 1.0f / g;
    const float thr = lam * inv_g;

    // geometric-kernel constants (uniform -> SGPR)
    const float aa   = al + 2.f*g;
    const float disc = sqrtf(aa*aa - 4.f*g*g);
    const float r    = sgpr_f((2.f*g) / (aa + disc));
    const float q    = sgpr_f(r*r*r*r*r);
    const float invq = sgpr_f(1.f / q);
    const float rn   = powf(r, (float)NCOL);
    const float factor = sgpr_f(1.f / (g * (1.f/r - r) * (1.f - rn)));
    const float r2 = sgpr_f(r*r), r3 = sgpr_f(r*r*r), r4 = sgpr_f(r*r*r*r);

    const bool act = (lane < 60);
    const int  j0  = lane * 5;
    const int  lprev = (lane == 0) ? 59 : lane - 1;
    const int  ll  = act ? lane : 0;          // clamped for LDS addressing

    // gated Hillis-Steele weights (window 8 lanes; q^8 = 2^-40 -> exact enough)
    const float q2 = q*q, q4 = q2*q2;
    const float wf1 = (lane>=1)?q:0.f, wf2=(lane>=2)?q2:0.f, wf4=(lane>=4)?q4:0.f;
    const float wb1 = (lane<=62)?q:0.f, wb2=(lane<=61)?q2:0.f, wb4=(lane<=59)?q4:0.f;
    const float vwF = powf(r, (float)(j0 + 1));
    const float vwB = act ? powf(r, (float)(296 - j0)) : 0.f;

    // G lane-slice in registers (45 VGPR); H lives in LDS (frees 45 VGPR -> occupancy)
    float Greg[MDIM][5];
    #pragma unroll
    for (int p = 0; p < MDIM; ++p) {
        #pragma unroll
        for (int i = 0; i < 5; ++i)
            Greg[p][i] = act ? ws[p*NCOL + j0 + i] : 0.f;
    }
    for (int i = tid; i < HPAD; i += BLOCK) Hs[i] = ws[WS_H + i];
    __syncthreads();   // one-time staging barrier

    const int gwave = blockIdx.x * WPB + wv;
    for (int rr = 0; rr < RPW; ++rr) {
        const int row = gwave * RPW + rr;
        float xc[5];
        {
            const float* xr = x0 + (size_t)row * NCOL + j0;
            #pragma unroll
            for (int i = 0; i < 5; ++i) xc[i] = act ? xr[i] : 0.f;
        }
        float xm = __shfl(xc[4], lprev);

        float bA[5] = {0.f,0.f,0.f,0.f,0.f};
        {
            const float* brow = b + (size_t)row * MDIM;
            #pragma unroll
            for (int p = 0; p < MDIM; ++p) {
                float bv = brow[p];
                if (act) {
                    #pragma unroll
                    for (int i = 0; i < 5; ++i)
                        bA[i] += bv * A[p*NCOL + j0 + i];
                }
            }
        }
        float eta[5] = {0.f,0.f,0.f,0.f,0.f};
        float tau[5] = {0.f,0.f,0.f,0.f,0.f};
        float u[5], wq[5];

        #pragma unroll
        for (int it = 0; it < NITER; ++it) {
            float rsd[5];
            if (act) {
                #pragma unroll
                for (int i = 0; i < 5; ++i) {
                    float xjm1 = (i == 0) ? xm : xc[i-1];
                    float xj = xc[i];
                    float dx = xjm1 - xj;
                    if (it > 0) {
                        eta[i] += g  * (dx - u[i]);
                        tau[i] += al * (xj - wq[i]);
                    }
                    float v  = dx + eta[i] * inv_g;
                    float av = fabsf(v) - thr;
                    u[i]  = (av > 0.f) ? copysignf(av, v) : 0.f;
                    wq[i] = fmaxf(xj + tau[i] * inv_al, 0.f);
                    rsd[i] = bA[i] + al*wq[i] - tau[i] + g*u[i] - eta[i];
                }
            } else {
                #pragma unroll
                for (int i = 0; i < 5; ++i) rsd[i] = 0.f;
            }

            // ---- resid @ Cinv via two geometric scans (exact, r from closed form) ----
            float l0 = rsd[0];
            float l1 = fmaf(r, l0, rsd[1]);
            float l2 = fmaf(r, l1, rsd[2]);
            float l3 = fmaf(r, l2, rsd[3]);
            float l4 = fmaf(r, l3, rsd[4]);
            float S = l4, P = S;
            P = fmaf(wf1, __shfl_up(P, 1), P);
            P = fmaf(wf2, __shfl_up(P, 2), P);
            P = fmaf(wf4, __shfl_up(P, 4), P);
            float E    = (P - S) * invq;
            float Ltot = readlane_f(P, 59);
            float m4 = rsd[4];
            float m3 = fmaf(r, m4, rsd[3]);
            float m2 = fmaf(r, m3, rsd[2]);
            float m1 = fmaf(r, m2, rsd[1]);
            float m0 = fmaf(r, m1, rsd[0]);
            float T = m0, Qs = T;
            Qs = fmaf(wb1, __shfl_down(Qs, 1), Qs);
            Qs = fmaf(wb2, __shfl_down(Qs, 2), Qs);
            Qs = fmaf(wb4, __shfl_down(Qs, 4), Qs);
            float Ep   = (Qs - T) * invq;
            float Atot = readlane_f(Qs, 0);

            float wF = vwF * Ltot;
            float wB = vwB * Atot;
            float y[5];
            y[0] = (l0 + r *E + wF   ) + (m0 + q *Ep + wB*r4) - rsd[0];
            y[1] = (l1 + r2*E + wF*r ) + (m1 + r4*Ep + wB*r3) - rsd[1];
            y[2] = (l2 + r3*E + wF*r2) + (m2 + r3*Ep + wB*r2) - rsd[2];
            y[3] = (l3 + r4*E + wF*r3) + (m3 + r2*Ep + wB*r ) - rsd[3];
            y[4] = (l4 + q *E + wF*r4) + (m4 + r *Ep + wB   ) - rsd[4];
            #pragma unroll
            for (int i = 0; i < 5; ++i) y[i] *= factor;

            // ---- rank-9 Woodbury: project (regs) -> DPP all-reduce -> correct (H from LDS) ----
            #pragma unroll
            for (int p = 0; p < MDIM; ++p) {
                float s =        rsd[0] * Greg[p][0];
                s = fmaf(rsd[1], Greg[p][1], s);
                s = fmaf(rsd[2], Greg[p][2], s);
                s = fmaf(rsd[3], Greg[p][3], s);
                s = fmaf(rsd[4], Greg[p][4], s);
                s = dpp_fadd<0x111>(s);   // row_shr:1
                s = dpp_fadd<0x112>(s);   // row_shr:2
                s = dpp_fadd<0x114>(s);   // row_shr:4
                s = dpp_fadd<0x118>(s);   // row_shr:8
                s = dpp_fadd<0x142>(s);   // row_bcast15
                s = dpp_fadd<0x143>(s);   // row_bcast31 -> lane 63 has full sum
                float tp = readlane_f(s, 63);      // SGPR broadcast
                const float* hp = &Hs[p*360 + ll*6];   // 24B-aligned lane slice
                float2 h01 = *(const float2*)(hp);
                float2 h23 = *(const float2*)(hp + 2);
                float  h4  = hp[4];
                y[0] = fmaf(-tp, h01.x, y[0]);
                y[1] = fmaf(-tp, h01.y, y[1]);
                y[2] = fmaf(-tp, h23.x, y[2]);
                y[3] = fmaf(-tp, h23.y, y[3]);
                y[4] = fmaf(-tp, h4,    y[4]);
            }

            xm = __shfl(y[4], lprev);
            #pragma unroll
            for (int i = 0; i < 5; ++i) xc[i] = y[i];
        }

        if (act) {
            float* orow = out + (size_t)row * NCOL + j0;
            #pragma unroll
            for (int i = 0; i < 5; ++i) orow[i] = xc[i];
        }
    }
}

extern "C" void kernel_launch(void* const* d_in, const int* in_sizes, int n_in,
                              void* d_out, int out_size, void* d_ws, size_t ws_size,
                              hipStream_t stream) {
    const float* b     = (const float*)d_in[0];
    // d_in[1] = target (unused, shape only)
    const float* x0    = (const float*)d_in[2];
    const float* A     = (const float*)d_in[3];
    const float* alpha = (const float*)d_in[4];
    const float* gamma = (const float*)d_in[5];
    const float* lam   = (const float*)d_in[6];
    float* out = (float*)d_out;
    float* ws  = (float*)d_ws;

    ladmm_pre_g<<<dim3((MDIM*NCOL + 255)/256), dim3(256), 0, stream>>>(A, alpha, gamma, ws);
    ladmm_pre_h<<<dim3(1), dim3(256), 0, stream>>>(A, ws);
    ladmm_main<<<dim3(NBLOCKS), dim3(BLOCK), 0, stream>>>(b, x0, A, alpha, gamma, lam, ws, out);
}

// Round 6
// 206.897 us; speedup vs baseline: 4.0399x; 2.0096x over previous
//
#include <hip/hip_runtime.h>
#include <math.h>

#define NROW 65536
#define NCOL 300
#define MDIM 9
#define NITER 5
#define BLOCK 256
#define WPB 4               // waves per block
#define RPW 8               // rows per wave
#define NBLOCKS (NROW / (WPB * RPW))   // 2048 -> 8192 waves

// ws float layout: [0,2700) = G (9x300 row-major); [2700,5400) = W = L^-1 G (9x300)
#define WS_W  (MDIM*NCOL)

// DPP sum step: s += dpp_perm(s), invalid sources contribute 0 (old=0, bound_ctrl)
template<int CTRL>
__device__ __forceinline__ float dpp_fadd(float s) {
    int v = __builtin_amdgcn_update_dpp(0, __float_as_int(s), CTRL, 0xF, 0xF, true);
    return s + __int_as_float(v);
}
__device__ __forceinline__ float readlane_f(float v, int l) {
    return __int_as_float(__builtin_amdgcn_readlane(__float_as_int(v), l));
}
__device__ __forceinline__ float sgpr_f(float v) {
    return __int_as_float(__builtin_amdgcn_readfirstlane(__float_as_int(v)));
}

// ---------- precompute, stage 1 (grid-parallel): G = A * Cinv ----------
__global__ __launch_bounds__(256)
void ladmm_pre_g(const float* __restrict__ A,
                 const float* __restrict__ alphap,
                 const float* __restrict__ gammap,
                 float* __restrict__ ws)
{
    __shared__ float As[MDIM*NCOL];
    __shared__ float karr[NCOL];
    const int tid = threadIdx.x;
    const double al = (double)alphap[0];
    const double g  = (double)gammap[0];
    const double a    = al + 2.0*g;
    const double disc = sqrt(a*a - 4.0*g*g);
    const double r    = (2.0*g) / (a + disc);
    const double rn   = pow(r, (double)NCOL);
    const double factor = 1.0 / (g * (1.0/r - r) * (1.0 - rn));

    for (int d = tid; d < NCOL; d += 256) {
        int dd = (d < NCOL - d) ? d : NCOL - d;
        karr[d] = (float)(factor * (pow(r,(double)dd) + pow(r,(double)(NCOL-dd))));
    }
    for (int i = tid; i < MDIM*NCOL; i += 256) As[i] = A[i];
    __syncthreads();
    const int e = blockIdx.x * 256 + tid;
    if (e < MDIM*NCOL) {
        const int p = e / NCOL, j = e - p*NCOL;
        float s = 0.f;
        for (int k = 0; k < NCOL; ++k) {
            int d = j - k; if (d < 0) d += NCOL;
            s += As[p*NCOL+k] * karr[d];
        }
        ws[e] = s;
    }
}

// ---------- precompute, stage 2: S = I + G A^T, Cholesky, W = L^-1 G ----------
__global__ __launch_bounds__(256)
void ladmm_pre_w(const float* __restrict__ A,
                 float* __restrict__ ws)
{
    __shared__ double Sd[MDIM*MDIM];
    __shared__ double Ld[MDIM*MDIM];
    const int tid = threadIdx.x;
    // S = I9 + G A^T  (SPD)
    if (tid < MDIM*MDIM) {
        int p = tid / MDIM, q = tid - p*MDIM;
        double s = (p == q) ? 1.0 : 0.0;
        for (int j = 0; j < NCOL; ++j)
            s += (double)ws[p*NCOL+j] * (double)A[q*NCOL+j];
        Sd[tid] = s;
    }
    __syncthreads();
    if (tid == 0) {
        // Cholesky S = L L^T (double, 9x9)
        double L[MDIM][MDIM];
        for (int i = 0; i < MDIM; ++i)
            for (int j = 0; j <= i; ++j) {
                double s = Sd[i*MDIM+j];
                for (int m = 0; m < j; ++m) s -= L[i][m]*L[j][m];
                L[i][j] = (i == j) ? sqrt(s) : s / L[j][j];
            }
        for (int i = 0; i < MDIM; ++i)
            for (int j = 0; j <= i; ++j) Ld[i*MDIM+j] = L[i][j];
    }
    __syncthreads();
    // W = L^-1 G, column-parallel forward solve (correction = W^T W)
    for (int j = tid; j < NCOL; j += 256) {
        double wcol[MDIM];
        for (int p = 0; p < MDIM; ++p) {
            double s = (double)ws[p*NCOL + j];
            for (int k = 0; k < p; ++k) s -= Ld[p*MDIM+k] * wcol[k];
            wcol[p] = s / Ld[p*MDIM+p];
            ws[WS_W + p*NCOL + j] = (float)wcol[p];
        }
    }
}

// ---------- main (no LDS at all) ----------
__global__ __launch_bounds__(BLOCK)
void ladmm_main(const float* __restrict__ b,
                const float* __restrict__ x0,
                const float* __restrict__ A,
                const float* __restrict__ alphap,
                const float* __restrict__ gammap,
                const float* __restrict__ lamp,
                const float* __restrict__ ws,
                float* __restrict__ out)
{
    const int tid  = threadIdx.x;
    const int lane = tid & 63;
    const int wv   = tid >> 6;

    const float al  = alphap[0];
    const float g   = gammap[0];
    const float lam = lamp[0];
    const float inv_al = 1.0f / al;
    const float inv_g  = 1.0f / g;
    const float thr = lam * inv_g;

    // geometric-kernel constants (uniform -> SGPR)
    const float aa   = al + 2.f*g;
    const float disc = sqrtf(aa*aa - 4.f*g*g);
    const float r    = sgpr_f((2.f*g) / (aa + disc));
    const float q    = sgpr_f(r*r*r*r*r);
    const float invq = sgpr_f(1.f / q);
    const float rn   = powf(r, (float)NCOL);
    const float factor = sgpr_f(1.f / (g * (1.f/r - r) * (1.f - rn)));
    const float r2 = sgpr_f(r*r), r3 = sgpr_f(r*r*r), r4 = sgpr_f(r*r*r*r);

    const bool act = (lane < 60);
    const int  j0  = lane * 5;
    const int  lprev = (lane == 0) ? 59 : lane - 1;

    // gated Hillis-Steele weights (window 8 lanes; q^8 = 2^-40 -> exact enough)
    const float q2 = q*q, q4 = q2*q2;
    const float wf1 = (lane>=1)?q:0.f, wf2=(lane>=2)?q2:0.f, wf4=(lane>=4)?q4:0.f;
    const float wb1 = (lane<=62)?q:0.f, wb2=(lane<=61)?q2:0.f, wb4=(lane<=59)?q4:0.f;
    const float vwF = powf(r, (float)(j0 + 1));
    const float vwB = act ? powf(r, (float)(296 - j0)) : 0.f;

    // single merged table W (correction = W^T W rsd): 45 VGPRs, no LDS anywhere
    float Wreg[MDIM][5];
    #pragma unroll
    for (int p = 0; p < MDIM; ++p) {
        #pragma unroll
        for (int i = 0; i < 5; ++i)
            Wreg[p][i] = act ? ws[WS_W + p*NCOL + j0 + i] : 0.f;
    }

    const int gwave = blockIdx.x * WPB + wv;
    for (int rr = 0; rr < RPW; ++rr) {
        const int row = gwave * RPW + rr;
        float xc[5];
        {
            const float* xr = x0 + (size_t)row * NCOL + j0;
            #pragma unroll
            for (int i = 0; i < 5; ++i) xc[i] = act ? xr[i] : 0.f;
        }
        float xm = __shfl(xc[4], lprev);

        float bA[5] = {0.f,0.f,0.f,0.f,0.f};
        {
            const float* brow = b + (size_t)row * MDIM;
            #pragma unroll
            for (int p = 0; p < MDIM; ++p) {
                float bv = brow[p];
                if (act) {
                    #pragma unroll
                    for (int i = 0; i < 5; ++i)
                        bA[i] += bv * A[p*NCOL + j0 + i];
                }
            }
        }
        float eta[5] = {0.f,0.f,0.f,0.f,0.f};
        float tau[5] = {0.f,0.f,0.f,0.f,0.f};
        float u[5], wq[5];

        #pragma unroll
        for (int it = 0; it < NITER; ++it) {
            float rsd[5];
            if (act) {
                #pragma unroll
                for (int i = 0; i < 5; ++i) {
                    float xjm1 = (i == 0) ? xm : xc[i-1];
                    float xj = xc[i];
                    float dx = xjm1 - xj;
                    if (it > 0) {
                        eta[i] += g  * (dx - u[i]);
                        tau[i] += al * (xj - wq[i]);
                    }
                    float v  = dx + eta[i] * inv_g;
                    float av = fabsf(v) - thr;
                    u[i]  = (av > 0.f) ? copysignf(av, v) : 0.f;
                    wq[i] = fmaxf(xj + tau[i] * inv_al, 0.f);
                    rsd[i] = bA[i] + al*wq[i] - tau[i] + g*u[i] - eta[i];
                }
            } else {
                #pragma unroll
                for (int i = 0; i < 5; ++i) rsd[i] = 0.f;
            }

            // ---- resid @ Cinv via two geometric scans (exact) ----
            float l0 = rsd[0];
            float l1 = fmaf(r, l0, rsd[1]);
            float l2 = fmaf(r, l1, rsd[2]);
            float l3 = fmaf(r, l2, rsd[3]);
            float l4 = fmaf(r, l3, rsd[4]);
            float S = l4, P = S;
            P = fmaf(wf1, __shfl_up(P, 1), P);
            P = fmaf(wf2, __shfl_up(P, 2), P);
            P = fmaf(wf4, __shfl_up(P, 4), P);
            float E    = (P - S) * invq;
            float Ltot = readlane_f(P, 59);
            float m4 = rsd[4];
            float m3 = fmaf(r, m4, rsd[3]);
            float m2 = fmaf(r, m3, rsd[2]);
            float m1 = fmaf(r, m2, rsd[1]);
            float m0 = fmaf(r, m1, rsd[0]);
            float T = m0, Qs = T;
            Qs = fmaf(wb1, __shfl_down(Qs, 1), Qs);
            Qs = fmaf(wb2, __shfl_down(Qs, 2), Qs);
            Qs = fmaf(wb4, __shfl_down(Qs, 4), Qs);
            float Ep   = (Qs - T) * invq;
            float Atot = readlane_f(Qs, 0);

            float wF = vwF * Ltot;
            float wB = vwB * Atot;
            float y[5];
            y[0] = (l0 + r *E + wF   ) + (m0 + q *Ep + wB*r4) - rsd[0];
            y[1] = (l1 + r2*E + wF*r ) + (m1 + r4*Ep + wB*r3) - rsd[1];
            y[2] = (l2 + r3*E + wF*r2) + (m2 + r3*Ep + wB*r2) - rsd[2];
            y[3] = (l3 + r4*E + wF*r3) + (m3 + r2*Ep + wB*r ) - rsd[3];
            y[4] = (l4 + q *E + wF*r4) + (m4 + r *Ep + wB   ) - rsd[4];
            #pragma unroll
            for (int i = 0; i < 5; ++i) y[i] *= factor;

            // ---- rank-9 Woodbury: project W, DPP all-reduce, correct W ----
            #pragma unroll
            for (int p = 0; p < MDIM; ++p) {
                float s =        rsd[0] * Wreg[p][0];
                s = fmaf(rsd[1], Wreg[p][1], s);
                s = fmaf(rsd[2], Wreg[p][2], s);
                s = fmaf(rsd[3], Wreg[p][3], s);
                s = fmaf(rsd[4], Wreg[p][4], s);
                s = dpp_fadd<0x111>(s);   // row_shr:1
                s = dpp_fadd<0x112>(s);   // row_shr:2
                s = dpp_fadd<0x114>(s);   // row_shr:4
                s = dpp_fadd<0x118>(s);   // row_shr:8
                s = dpp_fadd<0x142>(s);   // row_bcast15
                s = dpp_fadd<0x143>(s);   // row_bcast31 -> lane 63 has full sum
                float tp = readlane_f(s, 63);      // SGPR broadcast
                y[0] = fmaf(-tp, Wreg[p][0], y[0]);
                y[1] = fmaf(-tp, Wreg[p][1], y[1]);
                y[2] = fmaf(-tp, Wreg[p][2], y[2]);
                y[3] = fmaf(-tp, Wreg[p][3], y[3]);
                y[4] = fmaf(-tp, Wreg[p][4], y[4]);
            }

            xm = __shfl(y[4], lprev);
            #pragma unroll
            for (int i = 0; i < 5; ++i) xc[i] = y[i];
        }

        if (act) {
            float* orow = out + (size_t)row * NCOL + j0;
            #pragma unroll
            for (int i = 0; i < 5; ++i) orow[i] = xc[i];
        }
    }
}

extern "C" void kernel_launch(void* const* d_in, const int* in_sizes, int n_in,
                              void* d_out, int out_size, void* d_ws, size_t ws_size,
                              hipStream_t stream) {
    const float* b     = (const float*)d_in[0];
    // d_in[1] = target (unused, shape only)
    const float* x0    = (const float*)d_in[2];
    const float* A     = (const float*)d_in[3];
    const float* alpha = (const float*)d_in[4];
    const float* gamma = (const float*)d_in[5];
    const float* lam   = (const float*)d_in[6];
    float* out = (float*)d_out;
    float* ws  = (float*)d_ws;

    ladmm_pre_g<<<dim3((MDIM*NCOL + 255)/256), dim3(256), 0, stream>>>(A, alpha, gamma, ws);
    ladmm_pre_w<<<dim3(1), dim3(256), 0, stream>>>(A, ws);
    ladmm_main<<<dim3(NBLOCKS), dim3(BLOCK), 0, stream>>>(b, x0, A, alpha, gamma, lam, ws, out);
}

// Round 7
// 203.207 us; speedup vs baseline: 4.1132x; 1.0182x over previous
//
#include <hip/hip_runtime.h>
#include <math.h>

#define NROW 65536
#define NCOL 300
#define MDIM 9
#define NITER 5
#define BLOCK 256
#define WPB 4                     // waves per block
#define NBLOCKS_MAIN 1536         // 256 CU x 6 blocks/CU (VGPR=76->80 => 6 waves/SIMD)
#define TOTAL_WAVES (NBLOCKS_MAIN * WPB)   // 6144; waves grid-stride rows

// ws float layout: [0,2700) = G (9x300 row-major); [2700,5400) = W = L^-1 G (9x300)
#define WS_W  (MDIM*NCOL)

// DPP sum step: s += dpp_perm(s), invalid sources contribute 0 (old=0, bound_ctrl)
template<int CTRL>
__device__ __forceinline__ float dpp_fadd(float s) {
    int v = __builtin_amdgcn_update_dpp(0, __float_as_int(s), CTRL, 0xF, 0xF, true);
    return s + __int_as_float(v);
}
__device__ __forceinline__ float readlane_f(float v, int l) {
    return __int_as_float(__builtin_amdgcn_readlane(__float_as_int(v), l));
}
__device__ __forceinline__ float sgpr_f(float v) {
    return __int_as_float(__builtin_amdgcn_readfirstlane(__float_as_int(v)));
}

// ---------- precompute, stage 1 (grid-parallel): G = A * Cinv ----------
__global__ __launch_bounds__(256)
void ladmm_pre_g(const float* __restrict__ A,
                 const float* __restrict__ alphap,
                 const float* __restrict__ gammap,
                 float* __restrict__ ws)
{
    __shared__ float As[MDIM*NCOL];
    __shared__ float karr[NCOL];
    const int tid = threadIdx.x;
    const double al = (double)alphap[0];
    const double g  = (double)gammap[0];
    const double a    = al + 2.0*g;
    const double disc = sqrt(a*a - 4.0*g*g);
    const double r    = (2.0*g) / (a + disc);
    const double rn   = pow(r, (double)NCOL);
    const double factor = 1.0 / (g * (1.0/r - r) * (1.0 - rn));

    for (int d = tid; d < NCOL; d += 256) {
        int dd = (d < NCOL - d) ? d : NCOL - d;
        karr[d] = (float)(factor * (pow(r,(double)dd) + pow(r,(double)(NCOL-dd))));
    }
    for (int i = tid; i < MDIM*NCOL; i += 256) As[i] = A[i];
    __syncthreads();
    const int e = blockIdx.x * 256 + tid;
    if (e < MDIM*NCOL) {
        const int p = e / NCOL, j = e - p*NCOL;
        float s = 0.f;
        for (int k = 0; k < NCOL; ++k) {
            int d = j - k; if (d < 0) d += NCOL;
            s += As[p*NCOL+k] * karr[d];
        }
        ws[e] = s;
    }
}

// ---------- precompute, stage 2: S = I + G A^T, Cholesky, W = L^-1 G ----------
__global__ __launch_bounds__(256)
void ladmm_pre_w(const float* __restrict__ A,
                 float* __restrict__ ws)
{
    __shared__ double Sd[MDIM*MDIM];
    __shared__ double Ld[MDIM*MDIM];
    const int tid = threadIdx.x;
    // S = I9 + G A^T  (SPD)
    if (tid < MDIM*MDIM) {
        int p = tid / MDIM, q = tid - p*MDIM;
        double s = (p == q) ? 1.0 : 0.0;
        for (int j = 0; j < NCOL; ++j)
            s += (double)ws[p*NCOL+j] * (double)A[q*NCOL+j];
        Sd[tid] = s;
    }
    __syncthreads();
    if (tid == 0) {
        // Cholesky S = L L^T (double, 9x9)
        double L[MDIM][MDIM];
        for (int i = 0; i < MDIM; ++i)
            for (int j = 0; j <= i; ++j) {
                double s = Sd[i*MDIM+j];
                for (int m = 0; m < j; ++m) s -= L[i][m]*L[j][m];
                L[i][j] = (i == j) ? sqrt(s) : s / L[j][j];
            }
        for (int i = 0; i < MDIM; ++i)
            for (int j = 0; j <= i; ++j) Ld[i*MDIM+j] = L[i][j];
    }
    __syncthreads();
    // W = L^-1 G, column-parallel forward solve (correction = W^T W)
    for (int j = tid; j < NCOL; j += 256) {
        double wcol[MDIM];
        for (int p = 0; p < MDIM; ++p) {
            double s = (double)ws[p*NCOL + j];
            for (int k = 0; k < p; ++k) s -= Ld[p*MDIM+k] * wcol[k];
            wcol[p] = s / Ld[p*MDIM+p];
            ws[WS_W + p*NCOL + j] = (float)wcol[p];
        }
    }
}

// ---------- main (no LDS; grid-stride rows, capacity-matched grid) ----------
__global__ __launch_bounds__(BLOCK)
void ladmm_main(const float* __restrict__ b,
                const float* __restrict__ x0,
                const float* __restrict__ A,
                const float* __restrict__ alphap,
                const float* __restrict__ gammap,
                const float* __restrict__ lamp,
                const float* __restrict__ ws,
                float* __restrict__ out)
{
    const int tid  = threadIdx.x;
    const int lane = tid & 63;
    const int wv   = tid >> 6;

    const float al  = alphap[0];
    const float g   = gammap[0];
    const float lam = lamp[0];
    const float inv_al = 1.0f / al;
    const float inv_g  = 1.0f / g;
    const float thr = lam * inv_g;

    // geometric-kernel constants (uniform -> SGPR)
    const float aa   = al + 2.f*g;
    const float disc = sqrtf(aa*aa - 4.f*g*g);
    const float r    = sgpr_f((2.f*g) / (aa + disc));
    const float q    = sgpr_f(r*r*r*r*r);
    const float invq = sgpr_f(1.f / q);
    const float rn   = powf(r, (float)NCOL);
    const float factor = sgpr_f(1.f / (g * (1.f/r - r) * (1.f - rn)));
    const float r2 = sgpr_f(r*r), r3 = sgpr_f(r*r*r), r4 = sgpr_f(r*r*r*r);

    const bool act = (lane < 60);
    const int  j0  = lane * 5;
    const int  lprev = (lane == 0) ? 59 : lane - 1;

    // gated Hillis-Steele weights (window 8 lanes; q^8 = 2^-40 -> exact enough)
    const float q2 = q*q, q4 = q2*q2;
    const float wf1 = (lane>=1)?q:0.f, wf2=(lane>=2)?q2:0.f, wf4=(lane>=4)?q4:0.f;
    const float wb1 = (lane<=62)?q:0.f, wb2=(lane<=61)?q2:0.f, wb4=(lane<=59)?q4:0.f;
    const float vwF = powf(r, (float)(j0 + 1));
    const float vwB = act ? powf(r, (float)(296 - j0)) : 0.f;

    // single merged table W (correction = W^T W rsd): 45 VGPRs, no LDS anywhere
    float Wreg[MDIM][5];
    #pragma unroll
    for (int p = 0; p < MDIM; ++p) {
        #pragma unroll
        for (int i = 0; i < 5; ++i)
            Wreg[p][i] = act ? ws[WS_W + p*NCOL + j0 + i] : 0.f;
    }

    const int gwave = blockIdx.x * WPB + wv;
    for (int row = gwave; row < NROW; row += TOTAL_WAVES) {
        float xc[5];
        {
            const float* xr = x0 + (size_t)row * NCOL + j0;
            #pragma unroll
            for (int i = 0; i < 5; ++i) xc[i] = act ? xr[i] : 0.f;
        }
        float xm = __shfl(xc[4], lprev);

        float bA[5] = {0.f,0.f,0.f,0.f,0.f};
        {
            const float* brow = b + (size_t)row * MDIM;
            #pragma unroll
            for (int p = 0; p < MDIM; ++p) {
                float bv = brow[p];
                if (act) {
                    #pragma unroll
                    for (int i = 0; i < 5; ++i)
                        bA[i] += bv * A[p*NCOL + j0 + i];
                }
            }
        }
        float eta[5] = {0.f,0.f,0.f,0.f,0.f};
        float tau[5] = {0.f,0.f,0.f,0.f,0.f};
        float u[5], wq[5];

        #pragma unroll
        for (int it = 0; it < NITER; ++it) {
            float rsd[5];
            if (act) {
                #pragma unroll
                for (int i = 0; i < 5; ++i) {
                    float xjm1 = (i == 0) ? xm : xc[i-1];
                    float xj = xc[i];
                    float dx = xjm1 - xj;
                    if (it > 0) {
                        eta[i] += g  * (dx - u[i]);
                        tau[i] += al * (xj - wq[i]);
                    }
                    float v  = dx + eta[i] * inv_g;
                    float av = fabsf(v) - thr;
                    u[i]  = (av > 0.f) ? copysignf(av, v) : 0.f;
                    wq[i] = fmaxf(xj + tau[i] * inv_al, 0.f);
                    rsd[i] = bA[i] + al*wq[i] - tau[i] + g*u[i] - eta[i];
                }
            } else {
                #pragma unroll
                for (int i = 0; i < 5; ++i) rsd[i] = 0.f;
            }

            // ---- resid @ Cinv via two geometric scans (exact) ----
            float l0 = rsd[0];
            float l1 = fmaf(r, l0, rsd[1]);
            float l2 = fmaf(r, l1, rsd[2]);
            float l3 = fmaf(r, l2, rsd[3]);
            float l4 = fmaf(r, l3, rsd[4]);
            float S = l4, P = S;
            P = fmaf(wf1, __shfl_up(P, 1), P);
            P = fmaf(wf2, __shfl_up(P, 2), P);
            P = fmaf(wf4, __shfl_up(P, 4), P);
            float E    = (P - S) * invq;
            float Ltot = readlane_f(P, 59);
            float m4 = rsd[4];
            float m3 = fmaf(r, m4, rsd[3]);
            float m2 = fmaf(r, m3, rsd[2]);
            float m1 = fmaf(r, m2, rsd[1]);
            float m0 = fmaf(r, m1, rsd[0]);
            float T = m0, Qs = T;
            Qs = fmaf(wb1, __shfl_down(Qs, 1), Qs);
            Qs = fmaf(wb2, __shfl_down(Qs, 2), Qs);
            Qs = fmaf(wb4, __shfl_down(Qs, 4), Qs);
            float Ep   = (Qs - T) * invq;
            float Atot = readlane_f(Qs, 0);

            float wF = vwF * Ltot;
            float wB = vwB * Atot;
            float y[5];
            y[0] = (l0 + r *E + wF   ) + (m0 + q *Ep + wB*r4) - rsd[0];
            y[1] = (l1 + r2*E + wF*r ) + (m1 + r4*Ep + wB*r3) - rsd[1];
            y[2] = (l2 + r3*E + wF*r2) + (m2 + r3*Ep + wB*r2) - rsd[2];
            y[3] = (l3 + r4*E + wF*r3) + (m3 + r2*Ep + wB*r ) - rsd[3];
            y[4] = (l4 + q *E + wF*r4) + (m4 + r *Ep + wB   ) - rsd[4];
            #pragma unroll
            for (int i = 0; i < 5; ++i) y[i] *= factor;

            // ---- rank-9 Woodbury: project W, DPP all-reduce, correct W ----
            #pragma unroll
            for (int p = 0; p < MDIM; ++p) {
                float s =        rsd[0] * Wreg[p][0];
                s = fmaf(rsd[1], Wreg[p][1], s);
                s = fmaf(rsd[2], Wreg[p][2], s);
                s = fmaf(rsd[3], Wreg[p][3], s);
                s = fmaf(rsd[4], Wreg[p][4], s);
                s = dpp_fadd<0x111>(s);   // row_shr:1
                s = dpp_fadd<0x112>(s);   // row_shr:2
                s = dpp_fadd<0x114>(s);   // row_shr:4
                s = dpp_fadd<0x118>(s);   // row_shr:8
                s = dpp_fadd<0x142>(s);   // row_bcast15
                s = dpp_fadd<0x143>(s);   // row_bcast31 -> lane 63 has full sum
                float tp = readlane_f(s, 63);      // SGPR broadcast
                y[0] = fmaf(-tp, Wreg[p][0], y[0]);
                y[1] = fmaf(-tp, Wreg[p][1], y[1]);
                y[2] = fmaf(-tp, Wreg[p][2], y[2]);
                y[3] = fmaf(-tp, Wreg[p][3], y[3]);
                y[4] = fmaf(-tp, Wreg[p][4], y[4]);
            }

            xm = __shfl(y[4], lprev);
            #pragma unroll
            for (int i = 0; i < 5; ++i) xc[i] = y[i];
        }

        if (act) {
            float* orow = out + (size_t)row * NCOL + j0;
            #pragma unroll
            for (int i = 0; i < 5; ++i) orow[i] = xc[i];
        }
    }
}

extern "C" void kernel_launch(void* const* d_in, const int* in_sizes, int n_in,
                              void* d_out, int out_size, void* d_ws, size_t ws_size,
                              hipStream_t stream) {
    const float* b     = (const float*)d_in[0];
    // d_in[1] = target (unused, shape only)
    const float* x0    = (const float*)d_in[2];
    const float* A     = (const float*)d_in[3];
    const float* alpha = (const float*)d_in[4];
    const float* gamma = (const float*)d_in[5];
    const float* lam   = (const float*)d_in[6];
    float* out = (float*)d_out;
    float* ws  = (float*)d_ws;

    ladmm_pre_g<<<dim3((MDIM*NCOL + 255)/256), dim3(256), 0, stream>>>(A, alpha, gamma, ws);
    ladmm_pre_w<<<dim3(1), dim3(256), 0, stream>>>(A, ws);
    ladmm_main<<<dim3(NBLOCKS_MAIN), dim3(BLOCK), 0, stream>>>(b, x0, A, alpha, gamma, lam, ws, out);
}

// Round 8
// 198.610 us; speedup vs baseline: 4.2085x; 1.0231x over previous
//
#include <hip/hip_runtime.h>
#include <math.h>

#define NROW 65536
#define NCOL 300
#define MDIM 9
#define NITER 5
#define BLOCK 256
#define WPB 4                     // waves per block
#define NBLOCKS_MAIN 1536         // 256 CU x 6 blocks/CU; grid-stride rows
#define TOTAL_WAVES (NBLOCKS_MAIN * WPB)   // 6144

// ws float layout: [0,2700) = G (scratch); [2700,5400) = W' = (L^-1 G)/sqrt(factor);
//                  [5400,8100) = fA = factor * A
#define WS_W  (MDIM*NCOL)
#define WS_FA (2*MDIM*NCOL)

// DPP sum step: s += dpp_perm(s), invalid sources contribute 0 (old=0, bound_ctrl)
template<int CTRL>
__device__ __forceinline__ float dpp_fadd(float s) {
    int v = __builtin_amdgcn_update_dpp(0, __float_as_int(s), CTRL, 0xF, 0xF, true);
    return s + __int_as_float(v);
}
__device__ __forceinline__ float readlane_f(float v, int l) {
    return __int_as_float(__builtin_amdgcn_readlane(__float_as_int(v), l));
}
__device__ __forceinline__ float sgpr_f(float v) {
    return __int_as_float(__builtin_amdgcn_readfirstlane(__float_as_int(v)));
}

// ---------- precompute, stage 1 (grid-parallel): G = A * Cinv, fA = factor*A ----------
__global__ __launch_bounds__(256)
void ladmm_pre_g(const float* __restrict__ A,
                 const float* __restrict__ alphap,
                 const float* __restrict__ gammap,
                 float* __restrict__ ws)
{
    __shared__ float As[MDIM*NCOL];
    __shared__ float karr[NCOL];
    const int tid = threadIdx.x;
    const double al = (double)alphap[0];
    const double g  = (double)gammap[0];
    const double a    = al + 2.0*g;
    const double disc = sqrt(a*a - 4.0*g*g);
    const double r    = (2.0*g) / (a + disc);
    const double rn   = pow(r, (double)NCOL);
    const double factor = 1.0 / (g * (1.0/r - r) * (1.0 - rn));

    for (int d = tid; d < NCOL; d += 256) {
        int dd = (d < NCOL - d) ? d : NCOL - d;
        karr[d] = (float)(factor * (pow(r,(double)dd) + pow(r,(double)(NCOL-dd))));
    }
    for (int i = tid; i < MDIM*NCOL; i += 256) As[i] = A[i];
    __syncthreads();
    const int e = blockIdx.x * 256 + tid;
    if (e < MDIM*NCOL) {
        const int p = e / NCOL, j = e - p*NCOL;
        float s = 0.f;
        for (int k = 0; k < NCOL; ++k) {
            int d = j - k; if (d < 0) d += NCOL;
            s += As[p*NCOL+k] * karr[d];
        }
        ws[e] = s;
        ws[WS_FA + e] = (float)(factor * (double)As[e]);   // pre-scaled A for bA
    }
}

// ---------- precompute, stage 2: S = I + G A^T, Cholesky, W' = (L^-1 G)/sqrt(factor) ----------
__global__ __launch_bounds__(256)
void ladmm_pre_w(const float* __restrict__ A,
                 const float* __restrict__ alphap,
                 const float* __restrict__ gammap,
                 float* __restrict__ ws)
{
    __shared__ double Sd[MDIM*MDIM];
    __shared__ double Ld[MDIM*MDIM];
    const int tid = threadIdx.x;
    const double al = (double)alphap[0];
    const double g  = (double)gammap[0];
    const double a    = al + 2.0*g;
    const double disc = sqrt(a*a - 4.0*g*g);
    const double r    = (2.0*g) / (a + disc);
    const double rn   = pow(r, (double)NCOL);
    const double factor = 1.0 / (g * (1.0/r - r) * (1.0 - rn));
    const double isqf  = 1.0 / sqrt(factor);

    // S = I9 + G A^T  (SPD)
    if (tid < MDIM*MDIM) {
        int p = tid / MDIM, q = tid - p*MDIM;
        double s = (p == q) ? 1.0 : 0.0;
        for (int j = 0; j < NCOL; ++j)
            s += (double)ws[p*NCOL+j] * (double)A[q*NCOL+j];
        Sd[tid] = s;
    }
    __syncthreads();
    if (tid == 0) {
        // Cholesky S = L L^T (double, 9x9)
        double L[MDIM][MDIM];
        for (int i = 0; i < MDIM; ++i)
            for (int j = 0; j <= i; ++j) {
                double s = Sd[i*MDIM+j];
                for (int m = 0; m < j; ++m) s -= L[i][m]*L[j][m];
                L[i][j] = (i == j) ? sqrt(s) : s / L[j][j];
            }
        for (int i = 0; i < MDIM; ++i)
            for (int j = 0; j <= i; ++j) Ld[i*MDIM+j] = L[i][j];
    }
    __syncthreads();
    // W' = (L^-1 G)/sqrt(factor): with rs = factor*rsd, corr = W'^T (W' rs) = Woodbury exactly
    for (int j = tid; j < NCOL; j += 256) {
        double wcol[MDIM];
        for (int p = 0; p < MDIM; ++p) {
            double s = (double)ws[p*NCOL + j];
            for (int k = 0; k < p; ++k) s -= Ld[p*MDIM+k] * wcol[k];
            wcol[p] = s / Ld[p*MDIM+p];
            ws[WS_W + p*NCOL + j] = (float)(wcol[p] * isqf);
        }
    }
}

// ---------- main (no LDS; collapsed dual-state; factor folded into inputs) ----------
__global__ __launch_bounds__(BLOCK)
void ladmm_main(const float* __restrict__ b,
                const float* __restrict__ x0,
                const float* __restrict__ alphap,
                const float* __restrict__ gammap,
                const float* __restrict__ lamp,
                const float* __restrict__ ws,
                float* __restrict__ out)
{
    const int tid  = threadIdx.x;
    const int lane = tid & 63;
    const int wv   = tid >> 6;

    const float al  = alphap[0];
    const float g   = gammap[0];
    const float lam = lamp[0];
    const float thr = lam / g;

    // geometric-kernel constants (uniform -> SGPR)
    const float aa   = al + 2.f*g;
    const float disc = sqrtf(aa*aa - 4.f*g*g);
    const float r    = sgpr_f((2.f*g) / (aa + disc));
    const float q    = sgpr_f(r*r*r*r*r);
    const float invq = sgpr_f(1.f / q);
    const float rn   = powf(r, (float)NCOL);
    const float factor = sgpr_f(1.f / (g * (1.f/r - r) * (1.f - rn)));
    const float fal  = sgpr_f(factor * al);
    const float fg   = sgpr_f(factor * g);
    const float r2 = sgpr_f(r*r), r3 = sgpr_f(r*r*r), r4 = sgpr_f(r*r*r*r);

    const bool act = (lane < 60);
    const int  j0  = lane * 5;
    const int  lprev = (lane == 0) ? 59 : lane - 1;

    // gated Hillis-Steele weights (window 8 lanes; q^8 = 2^-40 -> exact enough)
    const float q2 = q*q, q4 = q2*q2;
    const float wf1 = (lane>=1)?q:0.f, wf2=(lane>=2)?q2:0.f, wf4=(lane>=4)?q4:0.f;
    const float wb1 = (lane<=62)?q:0.f, wb2=(lane<=61)?q2:0.f, wb4=(lane<=59)?q4:0.f;
    const float vwF = powf(r, (float)(j0 + 1));
    const float vwB = act ? powf(r, (float)(296 - j0)) : 0.f;

    // W' table in registers (45 VGPR); no LDS anywhere
    float Wreg[MDIM][5];
    #pragma unroll
    for (int p = 0; p < MDIM; ++p) {
        #pragma unroll
        for (int i = 0; i < 5; ++i)
            Wreg[p][i] = act ? ws[WS_W + p*NCOL + j0 + i] : 0.f;
    }
    const float* __restrict__ fA = ws + WS_FA;

    const int gwave = blockIdx.x * WPB + wv;
    for (int row = gwave; row < NROW; row += TOTAL_WAVES) {
        float xc[5];
        {
            const float* xr = x0 + (size_t)row * NCOL + j0;
            #pragma unroll
            for (int i = 0; i < 5; ++i) xc[i] = act ? xr[i] : 0.f;
        }
        float xm = __shfl(xc[4], lprev);

        // bA pre-scaled by factor (fA = factor*A)
        float bA[5] = {0.f,0.f,0.f,0.f,0.f};
        {
            const float* brow = b + (size_t)row * MDIM;
            #pragma unroll
            for (int p = 0; p < MDIM; ++p) {
                float bv = brow[p];
                if (act) {
                    #pragma unroll
                    for (int i = 0; i < 5; ++i)
                        bA[i] += bv * fA[p*NCOL + j0 + i];
                }
            }
        }
        // collapsed dual state: eh = c - dx (TV), th = min(pre,0) - x (nonneg)
        // init so that iter-1 reproduces eta=tau=0: eh0 = -dx0, th0 = -x0
        float eh[5], th[5];
        #pragma unroll
        for (int i = 0; i < 5; ++i) {
            float xjm1 = (i == 0) ? xm : xc[i-1];
            eh[i] = xc[i] - xjm1;
            th[i] = -xc[i];
        }

        #pragma unroll
        for (int it = 0; it < NITER; ++it) {
            float rs[5];
            if (act) {
                #pragma unroll
                for (int i = 0; i < 5; ++i) {
                    float xjm1 = (i == 0) ? xm : xc[i-1];
                    float xj = xc[i];
                    float dx  = xjm1 - xj;                      // 1
                    float v   = fmaf(2.f, dx, eh[i]);           // 1
                    float c   = fminf(fmaxf(v, -thr), thr);     // 1 (v_med3)
                    eh[i] = c - dx;                             // 1
                    float pre = fmaf(2.f, xj, th[i]);           // 1
                    float mn  = fminf(pre, 0.f);                // 1
                    th[i] = mn - xj;                            // 1
                    // rs = factor*rsd = fbA - fal*th' - fg*eh'
                    rs[i] = fmaf(-fal, th[i], fmaf(-fg, eh[i], bA[i]));  // 2
                }
            } else {
                #pragma unroll
                for (int i = 0; i < 5; ++i) rs[i] = 0.f;
            }

            // ---- rs @ Cinv_raw via two geometric scans (factor already folded in) ----
            float l0 = rs[0];
            float l1 = fmaf(r, l0, rs[1]);
            float l2 = fmaf(r, l1, rs[2]);
            float l3 = fmaf(r, l2, rs[3]);
            float l4 = fmaf(r, l3, rs[4]);
            float S = l4, P = S;
            P = fmaf(wf1, __shfl_up(P, 1), P);
            P = fmaf(wf2, __shfl_up(P, 2), P);
            P = fmaf(wf4, __shfl_up(P, 4), P);
            float E    = (P - S) * invq;
            float Ltot = readlane_f(P, 59);
            float m4 = rs[4];
            float m3 = fmaf(r, m4, rs[3]);
            float m2 = fmaf(r, m3, rs[2]);
            float m1 = fmaf(r, m2, rs[1]);
            float m0 = fmaf(r, m1, rs[0]);
            float T = m0, Qs = T;
            Qs = fmaf(wb1, __shfl_down(Qs, 1), Qs);
            Qs = fmaf(wb2, __shfl_down(Qs, 2), Qs);
            Qs = fmaf(wb4, __shfl_down(Qs, 4), Qs);
            float Ep   = (Qs - T) * invq;
            float Atot = readlane_f(Qs, 0);

            float wF = vwF * Ltot;
            float wB = vwB * Atot;
            float y[5];
            y[0] = (l0 + r *E + wF   ) + (m0 + q *Ep + wB*r4) - rs[0];
            y[1] = (l1 + r2*E + wF*r ) + (m1 + r4*Ep + wB*r3) - rs[1];
            y[2] = (l2 + r3*E + wF*r2) + (m2 + r3*Ep + wB*r2) - rs[2];
            y[3] = (l3 + r4*E + wF*r3) + (m3 + r2*Ep + wB*r ) - rs[3];
            y[4] = (l4 + q *E + wF*r4) + (m4 + r *Ep + wB   ) - rs[4];

            // ---- rank-9: project W', DPP all-reduce, correct W' (exactly Woodbury) ----
            #pragma unroll
            for (int p = 0; p < MDIM; ++p) {
                float s =       rs[0] * Wreg[p][0];
                s = fmaf(rs[1], Wreg[p][1], s);
                s = fmaf(rs[2], Wreg[p][2], s);
                s = fmaf(rs[3], Wreg[p][3], s);
                s = fmaf(rs[4], Wreg[p][4], s);
                s = dpp_fadd<0x111>(s);   // row_shr:1
                s = dpp_fadd<0x112>(s);   // row_shr:2
                s = dpp_fadd<0x114>(s);   // row_shr:4
                s = dpp_fadd<0x118>(s);   // row_shr:8
                s = dpp_fadd<0x142>(s);   // row_bcast15
                s = dpp_fadd<0x143>(s);   // row_bcast31 -> lane 63 has full sum
                float tp = readlane_f(s, 63);      // SGPR broadcast
                y[0] = fmaf(-tp, Wreg[p][0], y[0]);
                y[1] = fmaf(-tp, Wreg[p][1], y[1]);
                y[2] = fmaf(-tp, Wreg[p][2], y[2]);
                y[3] = fmaf(-tp, Wreg[p][3], y[3]);
                y[4] = fmaf(-tp, Wreg[p][4], y[4]);
            }

            xm = __shfl(y[4], lprev);
            #pragma unroll
            for (int i = 0; i < 5; ++i) xc[i] = y[i];
        }

        if (act) {
            float* orow = out + (size_t)row * NCOL + j0;
            #pragma unroll
            for (int i = 0; i < 5; ++i) orow[i] = xc[i];
        }
    }
}

extern "C" void kernel_launch(void* const* d_in, const int* in_sizes, int n_in,
                              void* d_out, int out_size, void* d_ws, size_t ws_size,
                              hipStream_t stream) {
    const float* b     = (const float*)d_in[0];
    // d_in[1] = target (unused, shape only)
    const float* x0    = (const float*)d_in[2];
    const float* A     = (const float*)d_in[3];
    const float* alpha = (const float*)d_in[4];
    const float* gamma = (const float*)d_in[5];
    const float* lam   = (const float*)d_in[6];
    float* out = (float*)d_out;
    float* ws  = (float*)d_ws;

    ladmm_pre_g<<<dim3((MDIM*NCOL + 255)/256), dim3(256), 0, stream>>>(A, alpha, gamma, ws);
    ladmm_pre_w<<<dim3(1), dim3(256), 0, stream>>>(A, alpha, gamma, ws);
    ladmm_main<<<dim3(NBLOCKS_MAIN), dim3(BLOCK), 0, stream>>>(b, x0, alpha, gamma, lam, ws, out);
}